// Round 4
// baseline (246.019 us; speedup 1.0000x reference)
//
#include <hip/hip_runtime.h>
#include <hip/hip_bf16.h>

#define D_MODEL 2048
#define N_HEAD 32
#define N_KV_HEAD 8
#define N_REP 4
#define D_K 64
#define S_LEN 1024
#define B_SZ 2
#define M_ROWS (B_SZ * S_LEN)      // 2048
#define KV_DIM (N_KV_HEAD * D_K)   // 512
#define QKV_N 3072                 // 2048 q | 512 k | 512 v
#define KOFF 2048
#define VOFF 2560
#define LOG2E 1.44269504088896f

typedef __attribute__((ext_vector_type(8))) short short8;   // 8 bf16 (4 VGPRs)
typedef __attribute__((ext_vector_type(4))) float f32x4;
typedef __attribute__((ext_vector_type(16))) float f32x16;

#define EXP2F(x) __builtin_amdgcn_exp2f(x)   // v_exp_f32 (2^x native)

__device__ inline unsigned short f2bf(float f) {  // RNE fp32 -> bf16 bits
    union { float f; unsigned int u; } x{f};
    unsigned int r = x.u + 0x7fffu + ((x.u >> 16) & 1u);
    return (unsigned short)(r >> 16);
}
__device__ inline float bf2f(unsigned short b) {
    union { unsigned int u; float f; } x; x.u = ((unsigned int)b) << 16; return x.f;
}
__device__ inline void store_c(float* p, float v) { *p = v; }
__device__ inline void store_c(unsigned short* p, float v) { *p = f2bf(v); }

// async 16B global -> LDS (global_load_lds_dwordx4)
__device__ inline void load_lds16(const unsigned short* g, unsigned short* l) {
    __builtin_amdgcn_global_load_lds(
        (const __attribute__((address_space(1))) unsigned int*)g,
        (__attribute__((address_space(3))) unsigned int*)l, 16, 0, 0);
}

// pack two fp32 -> one u32 of 2 bf16 (truncation) via v_perm_b32
__device__ __forceinline__ unsigned int permpack(float hi_f, float lo_f) {
    union { float f; unsigned int u; } a{hi_f}, b{lo_f};
    return __builtin_amdgcn_perm(a.u, b.u, 0x07060302u);
}

// ---------------- fused weight prep: all 4 W[K,N] fp32 -> Wt[N,2048] bf16 ------
__global__ __launch_bounds__(256) void wprep_kernel(
        const float* __restrict__ Wq_, const float* __restrict__ Wk_,
        const float* __restrict__ Wv_, const float* __restrict__ Wo_,
        unsigned short* __restrict__ WtQKV, unsigned short* __restrict__ WtO) {
    const float* src; unsigned short* dst; int N;
    switch (blockIdx.z) {
        case 0: src = Wq_; dst = WtQKV; N = D_MODEL; break;
        case 1: src = Wk_; dst = WtQKV + (size_t)KOFF * D_MODEL; N = KV_DIM; break;
        case 2: src = Wv_; dst = WtQKV + (size_t)VOFF * D_MODEL; N = KV_DIM; break;
        default: src = Wo_; dst = WtO; N = D_MODEL; break;
    }
    int n0 = blockIdx.x * 64;
    if (n0 >= N) return;
    int k0 = blockIdx.y * 64;
    int t = threadIdx.x;
    int n = n0 + (t >> 2);
    int ks = k0 + (t & 3) * 16;
    unsigned int pk[8];
#pragma unroll
    for (int i = 0; i < 8; i++) {
        float a = src[(size_t)(ks + 2 * i) * N + n];
        float b = src[(size_t)(ks + 2 * i + 1) * N + n];
        pk[i] = (unsigned int)f2bf(a) | ((unsigned int)f2bf(b) << 16);
    }
    uint4* d = (uint4*)&dst[(size_t)n * D_MODEL + ks];
    d[0] = make_uint4(pk[0], pk[1], pk[2], pk[3]);
    d[1] = make_uint4(pk[4], pk[5], pk[6], pk[7]);
}

// -------- fp32 -> bf16 cast (vectorized by 4) --------
__global__ void cast_bf_kernel(const float* __restrict__ src,
                               unsigned short* __restrict__ dst, int n4) {
    int idx = blockIdx.x * blockDim.x + threadIdx.x;
    if (idx >= n4) return;
    float4 v = ((const float4*)src)[idx];
    unsigned int lo = (unsigned int)f2bf(v.x) | ((unsigned int)f2bf(v.y) << 16);
    unsigned int hi = (unsigned int)f2bf(v.z) | ((unsigned int)f2bf(v.w) << 16);
    ((uint2*)dst)[idx] = make_uint2(lo, hi);
}

// -------- concat bias q|k|v (fp32) --------
__global__ void concat_bias_kernel(const float* __restrict__ bq, const float* __restrict__ bk,
                                   const float* __restrict__ bv, float* __restrict__ dst) {
    int i = blockIdx.x * blockDim.x + threadIdx.x;
    if (i >= QKV_N) return;
    dst[i] = (i < KOFF) ? bq[i] : (i < VOFF) ? bk[i - KOFF] : bv[i - VOFF];
}

// ---------------- bf16 GEMM: C[M,N] = A[M,K] * Bt[N,K]^T + bias ------
// BM=128, BN=128, BK=64 (m97-class tile), 256 thr = 4 waves (2x2);
// wave = 64x64 output (4x4 16x16x32 frags). XOR-swizzled LDS, width-16
// global_load_lds staging. 32 MFMA : 16 ds_read_b128 per K-step.
template <typename TC>
__global__ __launch_bounds__(256) void gemm_bf16_kernel(
        const unsigned short* __restrict__ A,   // [M][K] bf16
        const unsigned short* __restrict__ Bt,  // [N][K] bf16
        const float* __restrict__ bias,
        TC* __restrict__ C, int M, int N, int K) {
    __shared__ unsigned short As[128 * 64];
    __shared__ unsigned short Bs[128 * 64];
    const int tid = threadIdx.x, lane = tid & 63;
    const int w = tid >> 6, wm = w >> 1, wn = w & 1;
    const int quad = lane >> 4, lr = lane & 15;
    const int bm = blockIdx.y * 128, bn = blockIdx.x * 128;

    f32x4 acc[4][4];
#pragma unroll
    for (int i = 0; i < 4; i++)
#pragma unroll
        for (int j = 0; j < 4; j++) acc[i][j] = (f32x4){0.f, 0.f, 0.f, 0.f};

    for (int k0 = 0; k0 < K; k0 += 64) {
        __syncthreads();
#pragma unroll
        for (int it = 0; it < 4; it++) {
            int slot = it * 256 + tid;
            int row = slot >> 3;
            int qc = (slot & 7) ^ (row & 7);
            load_lds16(A + (size_t)(bm + row) * K + k0 + qc * 8, &As[slot * 8]);
        }
#pragma unroll
        for (int it = 0; it < 4; it++) {
            int slot = it * 256 + tid;
            int row = slot >> 3;
            int qc = (slot & 7) ^ (row & 7);
            load_lds16(Bt + (size_t)(bn + row) * K + k0 + qc * 8, &Bs[slot * 8]);
        }
        __syncthreads();
#pragma unroll
        for (int ks = 0; ks < 2; ks++) {
            short8 af[4], bf[4];
#pragma unroll
            for (int i = 0; i < 4; i++) {
                int row = wm * 64 + i * 16 + lr;
                af[i] = *(const short8*)&As[(row * 8 + ((ks * 4 + quad) ^ (lr & 7))) * 8];
            }
#pragma unroll
            for (int j = 0; j < 4; j++) {
                int row = wn * 64 + j * 16 + lr;
                bf[j] = *(const short8*)&Bs[(row * 8 + ((ks * 4 + quad) ^ (lr & 7))) * 8];
            }
#pragma unroll
            for (int i = 0; i < 4; i++)
#pragma unroll
                for (int j = 0; j < 4; j++)
                    acc[i][j] = __builtin_amdgcn_mfma_f32_16x16x32_bf16(af[i], bf[j], acc[i][j], 0, 0, 0);
        }
    }
#pragma unroll
    for (int i = 0; i < 4; i++) {
#pragma unroll
        for (int j = 0; j < 4; j++) {
            int col = bn + wn * 64 + j * 16 + lr;
            int row0 = bm + wm * 64 + i * 16 + quad * 4;
            float bj = bias[col];
#pragma unroll
            for (int r = 0; r < 4; r++)
                store_c(&C[(size_t)(row0 + r) * N + col], acc[i][j][r] + bj);
        }
    }
}

// -------- fused RoPE in-place on bf16 QKV buffer (q scaled by 0.125*log2e) -----
__global__ void rope_bf_kernel(unsigned short* __restrict__ t) {
    const int QI = M_ROWS * N_HEAD * 32;          // q items
    const int TOT = QI + M_ROWS * N_KV_HEAD * 32; // + k items
    int idx = blockIdx.x * blockDim.x + threadIdx.x;
    if (idx >= TOT) return;
    int col_off, n_heads;
    float scale;
    if (idx < QI) { col_off = 0; n_heads = N_HEAD; scale = 0.125f * LOG2E; }
    else { idx -= QI; col_off = KOFF; n_heads = N_KV_HEAD; scale = 1.0f; }
    int i = idx & 31;
    int hh = (idx >> 5) % n_heads;
    int r = idx / (32 * n_heads);
    int s = r % S_LEN;
    float inv_freq = EXP2F((float)i * -0.41524101186f);  // 2^(-i*2/64*log2(1e4))
    float ang = (float)s * inv_freq;
    float c = __cosf(ang), sn = __sinf(ang);
    unsigned short* p = t + (size_t)r * QKV_N + col_off + hh * D_K + 2 * i;
    float te = bf2f(p[0]), to = bf2f(p[1]);
    p[0] = f2bf((te * c - to * sn) * scale);
    p[1] = f2bf((te * sn + to * c) * scale);
}

// ---------------- MFMA flash attention: swapped-operand 32x32, in-reg softmax --
// Block = 256 thr = 4 waves; each wave owns 32 q-rows (block = 128-row q-tile).
// S^T = K*Q^T via mfma_32x32x16 -> lane holds one q-row's 32 scores per kh-half;
// softmax fully in registers (tree reduce + permlane32_swap, zero LDS ops);
// P packed to bf16 in-reg (v_perm + permlane32_swap); O^T = V^T*P^T so the
// online rescale is a lane-local scalar. LDS only stages K/V (+O transpose).
#define AST 72
struct Pre { uint4 k0, k1, v0, v1; };

__device__ __forceinline__ void issue_pre(const unsigned short* kb,
                                          const unsigned short* vb,
                                          int j0, int tid, Pre& p) {
    int f0 = tid, f1 = tid + 256;
    p.k0 = *(const uint4*)(kb + (size_t)(j0 + (f0 >> 3)) * QKV_N + (f0 & 7) * 8);
    p.k1 = *(const uint4*)(kb + (size_t)(j0 + (f1 >> 3)) * QKV_N + (f1 & 7) * 8);
    int kp = tid & 31, dg = tid >> 5;
    p.v0 = *(const uint4*)(vb + (size_t)(j0 + 2 * kp) * QKV_N + dg * 8);
    p.v1 = *(const uint4*)(vb + (size_t)(j0 + 2 * kp + 1) * QKV_N + dg * 8);
}
__device__ __forceinline__ void commit_pre(unsigned short* Ks, unsigned short* Vt,
                                           int tid, const Pre& p) {
    int f0 = tid, f1 = tid + 256;
    *(uint4*)&Ks[(f0 >> 3) * AST + (f0 & 7) * 8] = p.k0;
    *(uint4*)&Ks[(f1 >> 3) * AST + (f1 & 7) * 8] = p.k1;
    int kp = tid & 31, dg = tid >> 5;
    const unsigned short* ta = (const unsigned short*)&p.v0;
    const unsigned short* tb = (const unsigned short*)&p.v1;
#pragma unroll
    for (int i = 0; i < 8; i++) {
        unsigned int pk = (unsigned int)ta[i] | ((unsigned int)tb[i] << 16);
        *(unsigned int*)&Vt[(dg * 8 + i) * AST + 2 * kp] = pk;
    }
}

__global__ __launch_bounds__(256) void attn_mfma_kernel(
        const unsigned short* __restrict__ qkv,   // [M_ROWS][QKV_N] bf16
        unsigned short* __restrict__ obf) {       // [M_ROWS][D_MODEL] bf16
    __shared__ unsigned short SM[2 * 64 * AST];   // Ks | Vt (reused for O transpose)
    unsigned short* Ks = SM;
    unsigned short* Vt = SM + 64 * AST;
    const int tid = threadIdx.x;
    const int w = tid >> 6, lane = tid & 63;
    const int lq = lane & 31, hi = lane >> 5;
    const int hi8 = hi * 8, hi4 = hi * 4;
    const int h = blockIdx.y, b = blockIdx.z;
    const int kvh = h >> 2;
    const unsigned short* kb = qkv + (size_t)(b * S_LEN) * QKV_N + KOFF + kvh * D_K;
    const unsigned short* vb = qkv + (size_t)(b * S_LEN) * QKV_N + VOFF + kvh * D_K;

    // causal balance: co-resident blocks (ids 256 apart) differ in b -> flip qt
    const int qt = b ? 7 - (int)blockIdx.x : (int)blockIdx.x;   // 0..7
    const int nt = 2 * qt + 2;
    const int qw0 = qt * 128 + w * 32;   // this wave's first q-row
    const int qg = qw0 + lq;             // this lane's q-row

    short8 aq[4];   // Q[qg][d]: d = hi*8 + {0..7} + 16*step
    {
        const unsigned short* qp = qkv + (size_t)(b * S_LEN + qg) * QKV_N + h * D_K + hi8;
#pragma unroll
        for (int st = 0; st < 4; st++) aq[st] = *(const short8*)(qp + st * 16);
    }
    f32x16 oacc[2];   // O^T: col=q(lane), row=d=crow(r,hi)+32*dt
#pragma unroll
    for (int dt = 0; dt < 2; dt++)
#pragma unroll
        for (int r = 0; r < 16; r++) oacc[dt][r] = 0.f;
    float m = -1e30f, l = 0.f;

    Pre pre;
    issue_pre(kb, vb, 0, tid, pre);
    for (int t = 0; t < nt; t++) {
        __syncthreads();                       // prev compute done; LDS free
        commit_pre(Ks, Vt, tid, pre);          // regs -> LDS
        __syncthreads();                       // staging visible
        if (t + 1 < nt) issue_pre(kb, vb, (t + 1) * 64, tid, pre);  // overlap
        const int t64 = t * 64;
        if (t64 > qw0 + 31) continue;          // wave done; keep doing barriers

        // ---- S^T = K * Q^T  (rows k, cols q=lane) ----
        f32x16 s0, s1;
#pragma unroll
        for (int r = 0; r < 16; r++) { s0[r] = 0.f; s1[r] = 0.f; }
#pragma unroll
        for (int st = 0; st < 4; st++) {
            short8 k0 = *(const short8*)&Ks[lq * AST + st * 16 + hi8];
            short8 k1 = *(const short8*)&Ks[(32 + lq) * AST + st * 16 + hi8];
            s0 = __builtin_amdgcn_mfma_f32_32x32x16_bf16(k0, aq[st], s0, 0, 0, 0);
            s1 = __builtin_amdgcn_mfma_f32_32x32x16_bf16(k1, aq[st], s1, 0, 0, 0);
        }
        float px[32];   // idx = kh*16 + r; k_local = (r&3)+8*(r>>2)+4*hi+32*kh
#pragma unroll
        for (int r = 0; r < 16; r++) { px[r] = s0[r]; px[16 + r] = s1[r]; }
        if (t64 + 63 > qw0) {   // diag tile: causal mask
#pragma unroll
            for (int kh = 0; kh < 2; kh++)
#pragma unroll
                for (int r = 0; r < 16; r++) {
                    int kg = t64 + kh * 32 + ((r & 3) + 8 * (r >> 2)) + hi4;
                    if (kg > qg) px[kh * 16 + r] = -1e30f;
                }
        }
        // ---- row max: in-lane tree + one permlane pair-exchange ----
        float tm[16];
#pragma unroll
        for (int i = 0; i < 16; i++) tm[i] = fmaxf(px[i], px[i + 16]);
#pragma unroll
        for (int i = 0; i < 8; i++) tm[i] = fmaxf(tm[i], tm[i + 8]);
#pragma unroll
        for (int i = 0; i < 4; i++) tm[i] = fmaxf(tm[i], tm[i + 4]);
        float lmax = fmaxf(fmaxf(tm[0], tm[1]), fmaxf(tm[2], tm[3]));
        union { float f; unsigned int u; } mb{lmax};
        auto rr = __builtin_amdgcn_permlane32_swap((int)mb.u, (int)mb.u, false, false);
        union { unsigned int u; float f; } ra, rb;
        ra.u = (unsigned int)rr[0];
        rb.u = (unsigned int)rr[1];
        float mn = fmaxf(m, fmaxf(ra.f, rb.f));
        float corr = EXP2F(m - mn);
        m = mn;
        // ---- p = exp2(s - m); truncate to bf16 for P/l consistency ----
        float p[32], pm[32];
#pragma unroll
        for (int i = 0; i < 32; i++) {
            p[i] = EXP2F(px[i] - mn);
            union { float f; unsigned int u; } pu{p[i]};
            pu.u &= 0xFFFF0000u;
            pm[i] = pu.f;
        }
        // ---- row sum: in-lane tree + permlane pair-exchange ----
        float ts[16];
#pragma unroll
        for (int i = 0; i < 16; i++) ts[i] = pm[i] + pm[i + 16];
#pragma unroll
        for (int i = 0; i < 8; i++) ts[i] = ts[i] + ts[i + 8];
#pragma unroll
        for (int i = 0; i < 4; i++) ts[i] = ts[i] + ts[i + 4];
        float lsum = (ts[0] + ts[1]) + (ts[2] + ts[3]);
        union { float f; unsigned int u; } sb{lsum};
        auto rr2 = __builtin_amdgcn_permlane32_swap((int)sb.u, (int)sb.u, false, false);
        union { unsigned int u; float f; } sa2, sb2;
        sa2.u = (unsigned int)rr2[0];
        sb2.u = (unsigned int)rr2[1];
        l = l * corr + (sa2.f + sb2.f);
        // ---- rescale O (corr is lane-local: O^T has q on lanes) ----
#pragma unroll
        for (int dt = 0; dt < 2; dt++)
#pragma unroll
            for (int r = 0; r < 16; r++) oacc[dt][r] *= corr;
        // ---- pack P -> bf16 B-fragments (P^T: col=q, k = hi*8+e+16*sl) ----
        short8 pf[4];
#pragma unroll
        for (int kh = 0; kh < 2; kh++)
#pragma unroll
            for (int s = 0; s < 2; s++) {
                int base = kh * 16 + 8 * s;
                unsigned int a01 = permpack(p[base + 1], p[base + 0]);
                unsigned int a23 = permpack(p[base + 3], p[base + 2]);
                unsigned int a45 = permpack(p[base + 5], p[base + 4]);
                unsigned int a67 = permpack(p[base + 7], p[base + 6]);
                auto r02 = __builtin_amdgcn_permlane32_swap((int)a01, (int)a45, false, false);
                auto r13 = __builtin_amdgcn_permlane32_swap((int)a23, (int)a67, false, false);
                union { unsigned int wd[4]; short8 v; } pk;
                pk.wd[0] = (unsigned int)r02[0];
                pk.wd[1] = (unsigned int)r13[0];
                pk.wd[2] = (unsigned int)r02[1];
                pk.wd[3] = (unsigned int)r13[1];
                pf[kh * 2 + s] = pk.v;
            }
        // ---- O^T += V^T * P^T ----
#pragma unroll
        for (int dt = 0; dt < 2; dt++)
#pragma unroll
            for (int sl = 0; sl < 4; sl++) {
                short8 va = *(const short8*)&Vt[(dt * 32 + lq) * AST + sl * 16 + hi8];
                oacc[dt] = __builtin_amdgcn_mfma_f32_32x32x16_bf16(va, pf[sl], oacc[dt], 0, 0, 0);
            }
    }
    // ---- epilogue: O^T -> per-wave LDS transpose -> coalesced stores ----
    __syncthreads();                           // all waves done with Ks/Vt
    float inv = 1.f / l;
    unsigned short* Os = SM + w * 32 * AST;    // per-wave 32x72 region
#pragma unroll
    for (int dt = 0; dt < 2; dt++)
#pragma unroll
        for (int j = 0; j < 8; j++) {          // r = 2j, 2j+1 -> d, d+1
            int d = dt * 32 + ((2 * j) & 3) + 8 * (j >> 1) + hi4;
            unsigned int pk = (unsigned int)f2bf(oacc[dt][2 * j] * inv)
                            | ((unsigned int)f2bf(oacc[dt][2 * j + 1] * inv) << 16);
            *(unsigned int*)&Os[lq * AST + d] = pk;
        }
    __syncthreads();
#pragma unroll
    for (int j = 0; j < 4; j++) {
        int row = j * 8 + (lane >> 3);
        short8 v = *(const short8*)&Os[row * AST + (lane & 7) * 8];
        int qrow = b * S_LEN + qw0 + row;
        *(short8*)&obf[(size_t)qrow * D_MODEL + h * D_K + (lane & 7) * 8] = v;
    }
}

extern "C" void kernel_launch(void* const* d_in, const int* in_sizes, int n_in,
                              void* d_out, int out_size, void* d_ws, size_t ws_size,
                              hipStream_t stream) {
    const float* x  = (const float*)d_in[0];
    const float* Wq = (const float*)d_in[1];
    const float* bq = (const float*)d_in[2];
    const float* Wk = (const float*)d_in[3];
    const float* bk = (const float*)d_in[4];
    const float* Wv = (const float*)d_in[5];
    const float* bv = (const float*)d_in[6];
    const float* Wo = (const float*)d_in[7];
    const float* bo = (const float*)d_in[8];
    float* out = (float*)d_out;

    // ws (bf16 elems): xbf/obf 8MB | WtQKV 12MB | WtO 8MB | qkv 12MB | bias 12KB = 40MB
    unsigned short* xbf   = (unsigned short*)d_ws;                       // [2048][2048]
    unsigned short* WtQKV = xbf + (size_t)M_ROWS * D_MODEL;              // [3072][2048]
    unsigned short* WtO   = WtQKV + (size_t)QKV_N * D_MODEL;             // [2048][2048]
    unsigned short* qkv   = WtO + (size_t)D_MODEL * D_MODEL;             // [2048][3072]
    float* bias_qkv       = (float*)(qkv + (size_t)M_ROWS * QKV_N);      // [3072]
    unsigned short* obf   = xbf;  // xbf consumed by QKV GEMM before attn writes

    dim3 gb(256);

    cast_bf_kernel<<<(M_ROWS * D_MODEL / 4 + 255) / 256, gb, 0, stream>>>(x, xbf, M_ROWS * D_MODEL / 4);
    wprep_kernel<<<dim3(32, 32, 4), gb, 0, stream>>>(Wq, Wk, Wv, Wo, WtQKV, WtO);
    concat_bias_kernel<<<(QKV_N + 255) / 256, gb, 0, stream>>>(bq, bk, bv, bias_qkv);
    // fused QKV projection (bf16 out): 24 x 16 = 384 blocks
    gemm_bf16_kernel<unsigned short><<<dim3(QKV_N / 128, M_ROWS / 128), gb, 0, stream>>>(
        xbf, WtQKV, bias_qkv, qkv, M_ROWS, QKV_N, D_MODEL);
    // fused RoPE (q scaled by 0.125*log2e for exp2 softmax)
    rope_bf_kernel<<<(M_ROWS * (N_HEAD + N_KV_HEAD) * 32 + 255) / 256, gb, 0, stream>>>(qkv);
    // attention: 128-row q-tile per block, swapped-operand 32x32 MFMA, 512 blocks
    attn_mfma_kernel<<<dim3(8, N_HEAD, B_SZ), gb, 0, stream>>>(qkv, obf);
    // O projection (fp32 out): 16 x 16 = 256 blocks
    gemm_bf16_kernel<float><<<dim3(D_MODEL / 128, M_ROWS / 128), gb, 0, stream>>>(
        obf, WtO, bo, out, M_ROWS, D_MODEL, D_MODEL);
}

// Round 5
// 225.245 us; speedup vs baseline: 1.0922x; 1.0922x over previous
//
#include <hip/hip_runtime.h>
#include <hip/hip_bf16.h>

#define D_MODEL 2048
#define N_HEAD 32
#define N_KV_HEAD 8
#define N_REP 4
#define D_K 64
#define S_LEN 1024
#define B_SZ 2
#define M_ROWS (B_SZ * S_LEN)      // 2048
#define KV_DIM (N_KV_HEAD * D_K)   // 512
#define QKV_N 3072                 // 2048 q | 512 k | 512 v
#define KOFF 2048
#define VOFF 2560
#define LOG2E 1.44269504088896f
#define TAB_N (S_LEN * 32)         // rope cos/sin table entries

typedef __attribute__((ext_vector_type(8))) short short8;   // 8 bf16 (4 VGPRs)
typedef __attribute__((ext_vector_type(4))) float f32x4;
typedef __attribute__((ext_vector_type(16))) float f32x16;

#define EXP2F(x) __builtin_amdgcn_exp2f(x)   // v_exp_f32 (2^x native)

__device__ inline unsigned short f2bf(float f) {  // RNE fp32 -> bf16 bits
    union { float f; unsigned int u; } x{f};
    unsigned int r = x.u + 0x7fffu + ((x.u >> 16) & 1u);
    return (unsigned short)(r >> 16);
}
__device__ inline float bf2f(unsigned short b) {
    union { unsigned int u; float f; } x; x.u = ((unsigned int)b) << 16; return x.f;
}
__device__ inline void store_c(float* p, float v) { *p = v; }
__device__ inline void store_c(unsigned short* p, float v) { *p = f2bf(v); }

// async 16B global -> LDS (global_load_lds_dwordx4)
__device__ inline void load_lds16(const unsigned short* g, unsigned short* l) {
    __builtin_amdgcn_global_load_lds(
        (const __attribute__((address_space(1))) unsigned int*)g,
        (__attribute__((address_space(3))) unsigned int*)l, 16, 0, 0);
}

// pack two fp32 -> one u32 of 2 bf16 (truncation) via v_perm_b32
__device__ __forceinline__ unsigned int permpack(float hi_f, float lo_f) {
    union { float f; unsigned int u; } a{hi_f}, b{lo_f};
    return __builtin_amdgcn_perm(a.u, b.u, 0x07060302u);
}

// ---------------- fused weight prep: all 4 W[K,N] fp32 -> Wt[N,2048] bf16 ------
__global__ __launch_bounds__(256) void wprep_kernel(
        const float* __restrict__ Wq_, const float* __restrict__ Wk_,
        const float* __restrict__ Wv_, const float* __restrict__ Wo_,
        unsigned short* __restrict__ WtQKV, unsigned short* __restrict__ WtO) {
    const float* src; unsigned short* dst; int N;
    switch (blockIdx.z) {
        case 0: src = Wq_; dst = WtQKV; N = D_MODEL; break;
        case 1: src = Wk_; dst = WtQKV + (size_t)KOFF * D_MODEL; N = KV_DIM; break;
        case 2: src = Wv_; dst = WtQKV + (size_t)VOFF * D_MODEL; N = KV_DIM; break;
        default: src = Wo_; dst = WtO; N = D_MODEL; break;
    }
    int n0 = blockIdx.x * 64;
    if (n0 >= N) return;
    int k0 = blockIdx.y * 64;
    int t = threadIdx.x;
    int n = n0 + (t >> 2);
    int ks = k0 + (t & 3) * 16;
    unsigned int pk[8];
#pragma unroll
    for (int i = 0; i < 8; i++) {
        float a = src[(size_t)(ks + 2 * i) * N + n];
        float b = src[(size_t)(ks + 2 * i + 1) * N + n];
        pk[i] = (unsigned int)f2bf(a) | ((unsigned int)f2bf(b) << 16);
    }
    uint4* d = (uint4*)&dst[(size_t)n * D_MODEL + ks];
    d[0] = make_uint4(pk[0], pk[1], pk[2], pk[3]);
    d[1] = make_uint4(pk[4], pk[5], pk[6], pk[7]);
}

// -------- fp32 -> bf16 cast (vectorized by 4) --------
__global__ void cast_bf_kernel(const float* __restrict__ src,
                               unsigned short* __restrict__ dst, int n4) {
    int idx = blockIdx.x * blockDim.x + threadIdx.x;
    if (idx >= n4) return;
    float4 v = ((const float4*)src)[idx];
    unsigned int lo = (unsigned int)f2bf(v.x) | ((unsigned int)f2bf(v.y) << 16);
    unsigned int hi = (unsigned int)f2bf(v.z) | ((unsigned int)f2bf(v.w) << 16);
    ((uint2*)dst)[idx] = make_uint2(lo, hi);
}

// -------- concat bias q|k|v (fp32) + rope cos/sin table [1024][32] ------------
__global__ void prep_small_kernel(const float* __restrict__ bq, const float* __restrict__ bk,
                                  const float* __restrict__ bv, float* __restrict__ dst,
                                  float2* __restrict__ tab) {
    int i = blockIdx.x * blockDim.x + threadIdx.x;
    if (i < QKV_N) {
        dst[i] = (i < KOFF) ? bq[i] : (i < VOFF) ? bk[i - KOFF] : bv[i - VOFF];
    }
    int j = i - QKV_N;
    if (j >= 0 && j < TAB_N) {
        int s = j >> 5, p = j & 31;
        float invf = EXP2F((float)p * -0.41524101186f);  // theta^(-2p/64)
        float ang = (float)s * invf;
        tab[j] = make_float2(__cosf(ang), __sinf(ang));
    }
}

// ---------------- bf16 GEMM: C[M,N] = A[M,K] * Bt[N,K]^T + bias ------
// BM=128, BN=64, BK=64, 256 thr = 4 waves (2x2); wave = 64x32 (4x2 16x16x32 frags).
// ROPE=true (QKV projection): fused rotary embedding in the epilogue. The pair
// partner (col^1) lives in lane^1 (cols split on lr bit0, same quad); cos/sin
// from the precomputed [1024][32] table (L2-resident). q cols also scaled by
// 0.125*log2e for the exp2-based softmax.
template <typename TC, bool ROPE>
__global__ __launch_bounds__(256) void gemm_bf16_kernel(
        const unsigned short* __restrict__ A,   // [M][K] bf16
        const unsigned short* __restrict__ Bt,  // [N][K] bf16
        const float* __restrict__ bias,
        const float2* __restrict__ rtab,
        TC* __restrict__ C, int M, int N, int K) {
    __shared__ unsigned short As[128 * 64];
    __shared__ unsigned short Bs[64 * 64];
    const int tid = threadIdx.x, lane = tid & 63;
    const int w = tid >> 6, wm = w >> 1, wn = w & 1;
    const int quad = lane >> 4, lr = lane & 15;
    const int bm = blockIdx.y * 128, bn = blockIdx.x * 64;

    f32x4 acc[4][2];
#pragma unroll
    for (int i = 0; i < 4; i++)
#pragma unroll
        for (int j = 0; j < 2; j++) acc[i][j] = (f32x4){0.f, 0.f, 0.f, 0.f};

    for (int k0 = 0; k0 < K; k0 += 64) {
        __syncthreads();
#pragma unroll
        for (int it = 0; it < 4; it++) {
            int slot = it * 256 + tid;
            int row = slot >> 3;
            int qc = (slot & 7) ^ (row & 7);
            load_lds16(A + (size_t)(bm + row) * K + k0 + qc * 8, &As[slot * 8]);
        }
#pragma unroll
        for (int it = 0; it < 2; it++) {
            int slot = it * 256 + tid;
            int row = slot >> 3;
            int qc = (slot & 7) ^ (row & 7);
            load_lds16(Bt + (size_t)(bn + row) * K + k0 + qc * 8, &Bs[slot * 8]);
        }
        __syncthreads();
#pragma unroll
        for (int ks = 0; ks < 2; ks++) {
            short8 af[4], bf[2];
#pragma unroll
            for (int i = 0; i < 4; i++) {
                int row = wm * 64 + i * 16 + lr;
                af[i] = *(const short8*)&As[(row * 8 + ((ks * 4 + quad) ^ (lr & 7))) * 8];
            }
#pragma unroll
            for (int j = 0; j < 2; j++) {
                int row = wn * 32 + j * 16 + lr;
                bf[j] = *(const short8*)&Bs[(row * 8 + ((ks * 4 + quad) ^ (lr & 7))) * 8];
            }
#pragma unroll
            for (int i = 0; i < 4; i++)
#pragma unroll
                for (int j = 0; j < 2; j++)
                    acc[i][j] = __builtin_amdgcn_mfma_f32_16x16x32_bf16(af[i], bf[j], acc[i][j], 0, 0, 0);
        }
    }
#pragma unroll
    for (int i = 0; i < 4; i++) {
#pragma unroll
        for (int j = 0; j < 2; j++) {
            int col = bn + wn * 32 + j * 16 + lr;
            int row0 = bm + wm * 64 + i * 16 + quad * 4;
            float bj = bias[col];
            if constexpr (ROPE) {
                // col class is uniform across the shfl pair (boundaries % 64 == 0)
                bool isv = col >= VOFF;
                bool isq = col < KOFF;
                int ip = (col & 63) >> 1;
                bool even = !(lr & 1);
#pragma unroll
                for (int r = 0; r < 4; r++) {
                    float v = acc[i][j][r] + bj;
                    float pv = __shfl_xor(v, 1);     // partner col^1 (lane^1)
                    float outv = v;
                    if (!isv) {
                        int s = (row0 + r) & (S_LEN - 1);
                        float2 cs = rtab[s * 32 + ip];
                        outv = v * cs.x + (even ? -pv : pv) * cs.y;
                        if (isq) outv *= 0.125f * LOG2E;
                    }
                    store_c(&C[(size_t)(row0 + r) * N + col], outv);
                }
            } else {
#pragma unroll
                for (int r = 0; r < 4; r++)
                    store_c(&C[(size_t)(row0 + r) * N + col], acc[i][j][r] + bj);
            }
        }
    }
}

// ---------------- MFMA flash attention: swapped-operand 32x32, in-reg softmax --
// Block = 256 thr = 4 waves; each wave owns 32 q-rows (block = 128-row q-tile).
// S^T = K*Q^T via mfma_32x32x16 -> lane holds one q-row's 32 scores per kh-half;
// softmax fully in registers (tree reduce + permlane32_swap, zero LDS ops);
// P packed to bf16 in-reg (v_perm + permlane32_swap); O^T = V^T*P^T so the
// online rescale is a lane-local scalar. LDS only stages K/V (+O transpose).
#define AST 72
struct Pre { uint4 k0, k1, v0, v1; };

__device__ __forceinline__ void issue_pre(const unsigned short* kb,
                                          const unsigned short* vb,
                                          int j0, int tid, Pre& p) {
    int f0 = tid, f1 = tid + 256;
    p.k0 = *(const uint4*)(kb + (size_t)(j0 + (f0 >> 3)) * QKV_N + (f0 & 7) * 8);
    p.k1 = *(const uint4*)(kb + (size_t)(j0 + (f1 >> 3)) * QKV_N + (f1 & 7) * 8);
    int kp = tid & 31, dg = tid >> 5;
    p.v0 = *(const uint4*)(vb + (size_t)(j0 + 2 * kp) * QKV_N + dg * 8);
    p.v1 = *(const uint4*)(vb + (size_t)(j0 + 2 * kp + 1) * QKV_N + dg * 8);
}
__device__ __forceinline__ void commit_pre(unsigned short* Ks, unsigned short* Vt,
                                           int tid, const Pre& p) {
    int f0 = tid, f1 = tid + 256;
    *(uint4*)&Ks[(f0 >> 3) * AST + (f0 & 7) * 8] = p.k0;
    *(uint4*)&Ks[(f1 >> 3) * AST + (f1 & 7) * 8] = p.k1;
    int kp = tid & 31, dg = tid >> 5;
    const unsigned short* ta = (const unsigned short*)&p.v0;
    const unsigned short* tb = (const unsigned short*)&p.v1;
#pragma unroll
    for (int i = 0; i < 8; i++) {
        unsigned int pk = (unsigned int)ta[i] | ((unsigned int)tb[i] << 16);
        *(unsigned int*)&Vt[(dg * 8 + i) * AST + 2 * kp] = pk;
    }
}

__global__ __launch_bounds__(256) void attn_mfma_kernel(
        const unsigned short* __restrict__ qkv,   // [M_ROWS][QKV_N] bf16
        unsigned short* __restrict__ obf) {       // [M_ROWS][D_MODEL] bf16
    __shared__ unsigned short SM[2 * 64 * AST];   // Ks | Vt (reused for O transpose)
    unsigned short* Ks = SM;
    unsigned short* Vt = SM + 64 * AST;
    const int tid = threadIdx.x;
    const int w = tid >> 6, lane = tid & 63;
    const int lq = lane & 31, hi = lane >> 5;
    const int hi8 = hi * 8, hi4 = hi * 4;
    const int h = blockIdx.y, b = blockIdx.z;
    const int kvh = h >> 2;
    const unsigned short* kb = qkv + (size_t)(b * S_LEN) * QKV_N + KOFF + kvh * D_K;
    const unsigned short* vb = qkv + (size_t)(b * S_LEN) * QKV_N + VOFF + kvh * D_K;

    // causal balance: co-resident blocks (ids 256 apart) differ in b -> flip qt
    const int qt = b ? 7 - (int)blockIdx.x : (int)blockIdx.x;   // 0..7
    const int nt = 2 * qt + 2;
    const int qw0 = qt * 128 + w * 32;   // this wave's first q-row
    const int qg = qw0 + lq;             // this lane's q-row

    short8 aq[4];   // Q[qg][d]: d = hi*8 + {0..7} + 16*step
    {
        const unsigned short* qp = qkv + (size_t)(b * S_LEN + qg) * QKV_N + h * D_K + hi8;
#pragma unroll
        for (int st = 0; st < 4; st++) aq[st] = *(const short8*)(qp + st * 16);
    }
    f32x16 oacc[2];   // O^T: col=q(lane), row=d=crow(r,hi)+32*dt
#pragma unroll
    for (int dt = 0; dt < 2; dt++)
#pragma unroll
        for (int r = 0; r < 16; r++) oacc[dt][r] = 0.f;
    float m = -1e30f, l = 0.f;

    Pre pre;
    issue_pre(kb, vb, 0, tid, pre);
    for (int t = 0; t < nt; t++) {
        __syncthreads();                       // prev compute done; LDS free
        commit_pre(Ks, Vt, tid, pre);          // regs -> LDS
        __syncthreads();                       // staging visible
        if (t + 1 < nt) issue_pre(kb, vb, (t + 1) * 64, tid, pre);  // overlap
        const int t64 = t * 64;
        if (t64 > qw0 + 31) continue;          // wave done; keep doing barriers

        // ---- S^T = K * Q^T  (rows k, cols q=lane) ----
        f32x16 s0, s1;
#pragma unroll
        for (int r = 0; r < 16; r++) { s0[r] = 0.f; s1[r] = 0.f; }
#pragma unroll
        for (int st = 0; st < 4; st++) {
            short8 k0 = *(const short8*)&Ks[lq * AST + st * 16 + hi8];
            short8 k1 = *(const short8*)&Ks[(32 + lq) * AST + st * 16 + hi8];
            s0 = __builtin_amdgcn_mfma_f32_32x32x16_bf16(k0, aq[st], s0, 0, 0, 0);
            s1 = __builtin_amdgcn_mfma_f32_32x32x16_bf16(k1, aq[st], s1, 0, 0, 0);
        }
        float px[32];   // idx = kh*16 + r; k_local = (r&3)+8*(r>>2)+4*hi+32*kh
#pragma unroll
        for (int r = 0; r < 16; r++) { px[r] = s0[r]; px[16 + r] = s1[r]; }
        if (t64 + 63 > qw0) {   // diag tile: causal mask
#pragma unroll
            for (int kh = 0; kh < 2; kh++)
#pragma unroll
                for (int r = 0; r < 16; r++) {
                    int kg = t64 + kh * 32 + ((r & 3) + 8 * (r >> 2)) + hi4;
                    if (kg > qg) px[kh * 16 + r] = -1e30f;
                }
        }
        // ---- row max: in-lane tree + one permlane pair-exchange ----
        float tm[16];
#pragma unroll
        for (int i = 0; i < 16; i++) tm[i] = fmaxf(px[i], px[i + 16]);
#pragma unroll
        for (int i = 0; i < 8; i++) tm[i] = fmaxf(tm[i], tm[i + 8]);
#pragma unroll
        for (int i = 0; i < 4; i++) tm[i] = fmaxf(tm[i], tm[i + 4]);
        float lmax = fmaxf(fmaxf(tm[0], tm[1]), fmaxf(tm[2], tm[3]));
        union { float f; unsigned int u; } mb{lmax};
        auto rr = __builtin_amdgcn_permlane32_swap((int)mb.u, (int)mb.u, false, false);
        union { unsigned int u; float f; } ra, rb;
        ra.u = (unsigned int)rr[0];
        rb.u = (unsigned int)rr[1];
        float mn = fmaxf(m, fmaxf(ra.f, rb.f));
        float corr = EXP2F(m - mn);
        m = mn;
        // ---- p = exp2(s - m); truncate to bf16 for P/l consistency ----
        float p[32], pm[32];
#pragma unroll
        for (int i = 0; i < 32; i++) {
            p[i] = EXP2F(px[i] - mn);
            union { float f; unsigned int u; } pu{p[i]};
            pu.u &= 0xFFFF0000u;
            pm[i] = pu.f;
        }
        // ---- row sum: in-lane tree + permlane pair-exchange ----
        float ts[16];
#pragma unroll
        for (int i = 0; i < 16; i++) ts[i] = pm[i] + pm[i + 16];
#pragma unroll
        for (int i = 0; i < 8; i++) ts[i] = ts[i] + ts[i + 8];
#pragma unroll
        for (int i = 0; i < 4; i++) ts[i] = ts[i] + ts[i + 4];
        float lsum = (ts[0] + ts[1]) + (ts[2] + ts[3]);
        union { float f; unsigned int u; } sb{lsum};
        auto rr2 = __builtin_amdgcn_permlane32_swap((int)sb.u, (int)sb.u, false, false);
        union { unsigned int u; float f; } sa2, sb2;
        sa2.u = (unsigned int)rr2[0];
        sb2.u = (unsigned int)rr2[1];
        l = l * corr + (sa2.f + sb2.f);
        // ---- rescale O (corr is lane-local: O^T has q on lanes) ----
#pragma unroll
        for (int dt = 0; dt < 2; dt++)
#pragma unroll
            for (int r = 0; r < 16; r++) oacc[dt][r] *= corr;
        // ---- pack P -> bf16 B-fragments (P^T: col=q, k = hi*8+e+16*sl) ----
        short8 pf[4];
#pragma unroll
        for (int kh = 0; kh < 2; kh++)
#pragma unroll
            for (int s = 0; s < 2; s++) {
                int base = kh * 16 + 8 * s;
                unsigned int a01 = permpack(p[base + 1], p[base + 0]);
                unsigned int a23 = permpack(p[base + 3], p[base + 2]);
                unsigned int a45 = permpack(p[base + 5], p[base + 4]);
                unsigned int a67 = permpack(p[base + 7], p[base + 6]);
                auto r02 = __builtin_amdgcn_permlane32_swap((int)a01, (int)a45, false, false);
                auto r13 = __builtin_amdgcn_permlane32_swap((int)a23, (int)a67, false, false);
                union { unsigned int wd[4]; short8 v; } pk;
                pk.wd[0] = (unsigned int)r02[0];
                pk.wd[1] = (unsigned int)r13[0];
                pk.wd[2] = (unsigned int)r02[1];
                pk.wd[3] = (unsigned int)r13[1];
                pf[kh * 2 + s] = pk.v;
            }
        // ---- O^T += V^T * P^T ----
#pragma unroll
        for (int dt = 0; dt < 2; dt++)
#pragma unroll
            for (int sl = 0; sl < 4; sl++) {
                short8 va = *(const short8*)&Vt[(dt * 32 + lq) * AST + sl * 16 + hi8];
                oacc[dt] = __builtin_amdgcn_mfma_f32_32x32x16_bf16(va, pf[sl], oacc[dt], 0, 0, 0);
            }
    }
    // ---- epilogue: O^T -> per-wave LDS transpose -> coalesced stores ----
    __syncthreads();                           // all waves done with Ks/Vt
    float inv = 1.f / l;
    unsigned short* Os = SM + w * 32 * AST;    // per-wave 32x72 region
#pragma unroll
    for (int dt = 0; dt < 2; dt++)
#pragma unroll
        for (int j = 0; j < 8; j++) {          // r = 2j, 2j+1 -> d, d+1
            int d = dt * 32 + ((2 * j) & 3) + 8 * (j >> 1) + hi4;
            unsigned int pk = (unsigned int)f2bf(oacc[dt][2 * j] * inv)
                            | ((unsigned int)f2bf(oacc[dt][2 * j + 1] * inv) << 16);
            *(unsigned int*)&Os[lq * AST + d] = pk;
        }
    __syncthreads();
#pragma unroll
    for (int j = 0; j < 4; j++) {
        int row = j * 8 + (lane >> 3);
        short8 v = *(const short8*)&Os[row * AST + (lane & 7) * 8];
        int qrow = b * S_LEN + qw0 + row;
        *(short8*)&obf[(size_t)qrow * D_MODEL + h * D_K + (lane & 7) * 8] = v;
    }
}

extern "C" void kernel_launch(void* const* d_in, const int* in_sizes, int n_in,
                              void* d_out, int out_size, void* d_ws, size_t ws_size,
                              hipStream_t stream) {
    const float* x  = (const float*)d_in[0];
    const float* Wq = (const float*)d_in[1];
    const float* bq = (const float*)d_in[2];
    const float* Wk = (const float*)d_in[3];
    const float* bk = (const float*)d_in[4];
    const float* Wv = (const float*)d_in[5];
    const float* bv = (const float*)d_in[6];
    const float* Wo = (const float*)d_in[7];
    const float* bo = (const float*)d_in[8];
    float* out = (float*)d_out;

    // ws (bf16 elems): xbf/obf 8MB | WtQKV 12MB | WtO 8MB | qkv 12MB | bias 12KB
    //                 | rope table 256KB  = ~40.3MB
    unsigned short* xbf   = (unsigned short*)d_ws;                       // [2048][2048]
    unsigned short* WtQKV = xbf + (size_t)M_ROWS * D_MODEL;              // [3072][2048]
    unsigned short* WtO   = WtQKV + (size_t)QKV_N * D_MODEL;             // [2048][2048]
    unsigned short* qkv   = WtO + (size_t)D_MODEL * D_MODEL;             // [2048][3072]
    float* bias_qkv       = (float*)(qkv + (size_t)M_ROWS * QKV_N);      // [3072]
    float2* rtab          = (float2*)(bias_qkv + QKV_N);                 // [1024][32]
    unsigned short* obf   = xbf;  // xbf consumed by QKV GEMM before attn writes

    dim3 gb(256);

    cast_bf_kernel<<<(M_ROWS * D_MODEL / 4 + 255) / 256, gb, 0, stream>>>(x, xbf, M_ROWS * D_MODEL / 4);
    wprep_kernel<<<dim3(32, 32, 4), gb, 0, stream>>>(Wq, Wk, Wv, Wo, WtQKV, WtO);
    prep_small_kernel<<<(QKV_N + TAB_N + 255) / 256, gb, 0, stream>>>(bq, bk, bv, bias_qkv, rtab);
    // fused QKV projection + RoPE (bf16 out): 48 x 16 = 768 blocks
    gemm_bf16_kernel<unsigned short, true><<<dim3(QKV_N / 64, M_ROWS / 128), gb, 0, stream>>>(
        xbf, WtQKV, bias_qkv, rtab, qkv, M_ROWS, QKV_N, D_MODEL);
    // attention: 128-row q-tile per block, swapped-operand 32x32 MFMA, 512 blocks
    attn_mfma_kernel<<<dim3(8, N_HEAD, B_SZ), gb, 0, stream>>>(qkv, obf);
    // O projection (fp32 out): 32 x 16 = 512 blocks
    gemm_bf16_kernel<float, false><<<dim3(D_MODEL / 64, M_ROWS / 128), gb, 0, stream>>>(
        obf, WtO, bo, nullptr, out, M_ROWS, D_MODEL, D_MODEL);
}

// Round 7
// 220.698 us; speedup vs baseline: 1.1147x; 1.0206x over previous
//
#include <hip/hip_runtime.h>
#include <hip/hip_bf16.h>

#define D_MODEL 2048
#define N_HEAD 32
#define N_KV_HEAD 8
#define N_REP 4
#define D_K 64
#define S_LEN 1024
#define B_SZ 2
#define M_ROWS (B_SZ * S_LEN)      // 2048
#define KV_DIM (N_KV_HEAD * D_K)   // 512
#define QKV_N 3072                 // 2048 q | 512 k | 512 v
#define KOFF 2048
#define VOFF 2560
#define LOG2E 1.44269504088896f
#define TAB_N (S_LEN * 32)         // rope cos/sin table entries

typedef __attribute__((ext_vector_type(8))) short short8;   // 8 bf16 (4 VGPRs)
typedef __attribute__((ext_vector_type(4))) float f32x4;
typedef __attribute__((ext_vector_type(16))) float f32x16;

#define EXP2F(x) __builtin_amdgcn_exp2f(x)   // v_exp_f32 (2^x native)

__device__ inline unsigned short f2bf(float f) {  // RNE fp32 -> bf16 bits
    union { float f; unsigned int u; } x{f};
    unsigned int r = x.u + 0x7fffu + ((x.u >> 16) & 1u);
    return (unsigned short)(r >> 16);
}
__device__ inline float bf2f(unsigned short b) {
    union { unsigned int u; float f; } x; x.u = ((unsigned int)b) << 16; return x.f;
}
__device__ inline void store_c(float* p, float v) { *p = v; }
__device__ inline void store_c(unsigned short* p, float v) { *p = f2bf(v); }

// async 16B global -> LDS (global_load_lds_dwordx4)
__device__ inline void load_lds16(const unsigned short* g, unsigned short* l) {
    __builtin_amdgcn_global_load_lds(
        (const __attribute__((address_space(1))) unsigned int*)g,
        (__attribute__((address_space(3))) unsigned int*)l, 16, 0, 0);
}

// pack two fp32 -> one u32 of 2 bf16 (truncation) via v_perm_b32
__device__ __forceinline__ unsigned int permpack(float hi_f, float lo_f) {
    union { float f; unsigned int u; } a{hi_f}, b{lo_f};
    return __builtin_amdgcn_perm(a.u, b.u, 0x07060302u);
}

// ---------------- fused weight prep: all 4 W[K,N] fp32 -> Wt[N,2048] bf16 ------
__global__ __launch_bounds__(256) void wprep_kernel(
        const float* __restrict__ Wq_, const float* __restrict__ Wk_,
        const float* __restrict__ Wv_, const float* __restrict__ Wo_,
        unsigned short* __restrict__ WtQKV, unsigned short* __restrict__ WtO) {
    const float* src; unsigned short* dst; int N;
    switch (blockIdx.z) {
        case 0: src = Wq_; dst = WtQKV; N = D_MODEL; break;
        case 1: src = Wk_; dst = WtQKV + (size_t)KOFF * D_MODEL; N = KV_DIM; break;
        case 2: src = Wv_; dst = WtQKV + (size_t)VOFF * D_MODEL; N = KV_DIM; break;
        default: src = Wo_; dst = WtO; N = D_MODEL; break;
    }
    int n0 = blockIdx.x * 64;
    if (n0 >= N) return;
    int k0 = blockIdx.y * 64;
    int t = threadIdx.x;
    int n = n0 + (t >> 2);
    int ks = k0 + (t & 3) * 16;
    unsigned int pk[8];
#pragma unroll
    for (int i = 0; i < 8; i++) {
        float a = src[(size_t)(ks + 2 * i) * N + n];
        float b = src[(size_t)(ks + 2 * i + 1) * N + n];
        pk[i] = (unsigned int)f2bf(a) | ((unsigned int)f2bf(b) << 16);
    }
    uint4* d = (uint4*)&dst[(size_t)n * D_MODEL + ks];
    d[0] = make_uint4(pk[0], pk[1], pk[2], pk[3]);
    d[1] = make_uint4(pk[4], pk[5], pk[6], pk[7]);
}

// -------- fp32 -> bf16 cast (vectorized by 4) --------
__global__ void cast_bf_kernel(const float* __restrict__ src,
                               unsigned short* __restrict__ dst, int n4) {
    int idx = blockIdx.x * blockDim.x + threadIdx.x;
    if (idx >= n4) return;
    float4 v = ((const float4*)src)[idx];
    unsigned int lo = (unsigned int)f2bf(v.x) | ((unsigned int)f2bf(v.y) << 16);
    unsigned int hi = (unsigned int)f2bf(v.z) | ((unsigned int)f2bf(v.w) << 16);
    ((uint2*)dst)[idx] = make_uint2(lo, hi);
}

// -------- concat bias q|k|v (fp32) + rope cos/sin table [1024][32] ------------
__global__ void prep_small_kernel(const float* __restrict__ bq, const float* __restrict__ bk,
                                  const float* __restrict__ bv, float* __restrict__ dst,
                                  float2* __restrict__ tab) {
    int i = blockIdx.x * blockDim.x + threadIdx.x;
    if (i < QKV_N) {
        dst[i] = (i < KOFF) ? bq[i] : (i < VOFF) ? bk[i - KOFF] : bv[i - VOFF];
    }
    int j = i - QKV_N;
    if (j >= 0 && j < TAB_N) {
        int s = j >> 5, p = j & 31;
        float invf = EXP2F((float)p * -0.41524101186f);  // theta^(-2p/64)
        float ang = (float)s * invf;
        tab[j] = make_float2(__cosf(ang), __sinf(ang));
    }
}

// ---------------- bf16 GEMM: C[M,N] = A[M,K] * Bt[N,K]^T + bias ------
// BM=128, BN=64, BK=128, 256 thr = 4 waves (2x2); wave = 64x32 (4x2 16x16x32).
// BK=128 halves the barrier-drain count (16 K-steps) vs BK=64; LDS 48 KB keeps
// 3 blocks/CU (144 KB < 160 KB). XOR-swizzled chunks (c ^= row&7), conflict-free.
// ROPE=true (QKV projection): fused rotary embedding in the epilogue. The pair
// partner (col^1) lives in lane^1 (cols split on lr bit0, same quad); cos/sin
// from the precomputed [1024][32] table (L2-resident). q cols also scaled by
// 0.125*log2e for the exp2-based softmax.
template <typename TC, bool ROPE>
__global__ __launch_bounds__(256) void gemm_bf16_kernel(
        const unsigned short* __restrict__ A,   // [M][K] bf16
        const unsigned short* __restrict__ Bt,  // [N][K] bf16
        const float* __restrict__ bias,
        const float2* __restrict__ rtab,
        TC* __restrict__ C, int M, int N, int K) {
    __shared__ unsigned short As[128 * 128];   // 32 KB
    __shared__ unsigned short Bs[64 * 128];    // 16 KB
    const int tid = threadIdx.x, lane = tid & 63;
    const int w = tid >> 6, wm = w >> 1, wn = w & 1;
    const int quad = lane >> 4, lr = lane & 15;
    const int bm = blockIdx.y * 128, bn = blockIdx.x * 64;

    f32x4 acc[4][2];
#pragma unroll
    for (int i = 0; i < 4; i++)
#pragma unroll
        for (int j = 0; j < 2; j++) acc[i][j] = (f32x4){0.f, 0.f, 0.f, 0.f};

    for (int k0 = 0; k0 < K; k0 += 128) {
        __syncthreads();
        // A tile: 128 rows x 16 chunks (of 8 bf16); phys chunk p holds logical p^(row&7)
#pragma unroll
        for (int it = 0; it < 8; it++) {
            int slot = it * 256 + tid;
            int row = slot >> 4;
            int qc = (slot & 15) ^ (row & 7);
            load_lds16(A + (size_t)(bm + row) * K + k0 + qc * 8, &As[slot * 8]);
        }
        // B tile: 64 rows x 16 chunks
#pragma unroll
        for (int it = 0; it < 4; it++) {
            int slot = it * 256 + tid;
            int row = slot >> 4;
            int qc = (slot & 15) ^ (row & 7);
            load_lds16(Bt + (size_t)(bn + row) * K + k0 + qc * 8, &Bs[slot * 8]);
        }
        __syncthreads();
#pragma unroll
        for (int ks = 0; ks < 4; ks++) {
            short8 af[4], bf[2];
#pragma unroll
            for (int i = 0; i < 4; i++) {
                int row = wm * 64 + i * 16 + lr;
                af[i] = *(const short8*)&As[(row * 16 + ((ks * 4 + quad) ^ (lr & 7))) * 8];
            }
#pragma unroll
            for (int j = 0; j < 2; j++) {
                int row = wn * 32 + j * 16 + lr;
                bf[j] = *(const short8*)&Bs[(row * 16 + ((ks * 4 + quad) ^ (lr & 7))) * 8];
            }
#pragma unroll
            for (int i = 0; i < 4; i++)
#pragma unroll
                for (int j = 0; j < 2; j++)
                    acc[i][j] = __builtin_amdgcn_mfma_f32_16x16x32_bf16(af[i], bf[j], acc[i][j], 0, 0, 0);
        }
    }
#pragma unroll
    for (int i = 0; i < 4; i++) {
#pragma unroll
        for (int j = 0; j < 2; j++) {
            int col = bn + wn * 32 + j * 16 + lr;
            int row0 = bm + wm * 64 + i * 16 + quad * 4;
            float bj = bias[col];
            if constexpr (ROPE) {
                // col class is uniform across the shfl pair (boundaries % 64 == 0)
                bool isv = col >= VOFF;
                bool isq = col < KOFF;
                int ip = (col & 63) >> 1;
                bool even = !(lr & 1);
#pragma unroll
                for (int r = 0; r < 4; r++) {
                    float v = acc[i][j][r] + bj;
                    float pv = __shfl_xor(v, 1);     // partner col^1 (lane^1)
                    float outv = v;
                    if (!isv) {
                        int s = (row0 + r) & (S_LEN - 1);
                        float2 cs = rtab[s * 32 + ip];
                        outv = v * cs.x + (even ? -pv : pv) * cs.y;
                        if (isq) outv *= 0.125f * LOG2E;
                    }
                    store_c(&C[(size_t)(row0 + r) * N + col], outv);
                }
            } else {
#pragma unroll
                for (int r = 0; r < 4; r++)
                    store_c(&C[(size_t)(row0 + r) * N + col], acc[i][j][r] + bj);
            }
        }
    }
}

// ---------------- MFMA flash attention: swapped-operand 32x32, in-reg softmax --
// Block = 256 thr = 4 waves; each wave owns 32 q-rows (block = 128-row q-tile).
// S^T = K*Q^T via mfma_32x32x16 -> lane holds one q-row's 32 scores per kh-half;
// softmax fully in registers (tree reduce + permlane32_swap, zero LDS ops);
// P packed to bf16 in-reg (v_perm + permlane32_swap); O^T = V^T*P^T so the
// online rescale is a lane-local scalar. T5 setprio around MFMA clusters;
// T13 defer-max (THR=8 in log2 units) skips the O-rescale when max growth small.
#define AST 72
#define RESCALE_THR 8.0f
struct Pre { uint4 k0, k1, v0, v1; };

__device__ __forceinline__ void issue_pre(const unsigned short* kb,
                                          const unsigned short* vb,
                                          int j0, int tid, Pre& p) {
    int f0 = tid, f1 = tid + 256;
    p.k0 = *(const uint4*)(kb + (size_t)(j0 + (f0 >> 3)) * QKV_N + (f0 & 7) * 8);
    p.k1 = *(const uint4*)(kb + (size_t)(j0 + (f1 >> 3)) * QKV_N + (f1 & 7) * 8);
    int kp = tid & 31, dg = tid >> 5;
    p.v0 = *(const uint4*)(vb + (size_t)(j0 + 2 * kp) * QKV_N + dg * 8);
    p.v1 = *(const uint4*)(vb + (size_t)(j0 + 2 * kp + 1) * QKV_N + dg * 8);
}
__device__ __forceinline__ void commit_pre(unsigned short* Ks, unsigned short* Vt,
                                           int tid, const Pre& p) {
    int f0 = tid, f1 = tid + 256;
    *(uint4*)&Ks[(f0 >> 3) * AST + (f0 & 7) * 8] = p.k0;
    *(uint4*)&Ks[(f1 >> 3) * AST + (f1 & 7) * 8] = p.k1;
    int kp = tid & 31, dg = tid >> 5;
    const unsigned short* ta = (const unsigned short*)&p.v0;
    const unsigned short* tb = (const unsigned short*)&p.v1;
#pragma unroll
    for (int i = 0; i < 8; i++) {
        unsigned int pk = (unsigned int)ta[i] | ((unsigned int)tb[i] << 16);
        *(unsigned int*)&Vt[(dg * 8 + i) * AST + 2 * kp] = pk;
    }
}

__global__ __launch_bounds__(256) void attn_mfma_kernel(
        const unsigned short* __restrict__ qkv,   // [M_ROWS][QKV_N] bf16
        unsigned short* __restrict__ obf) {       // [M_ROWS][D_MODEL] bf16
    __shared__ unsigned short SM[2 * 64 * AST];   // Ks | Vt (reused for O transpose)
    unsigned short* Ks = SM;
    unsigned short* Vt = SM + 64 * AST;
    const int tid = threadIdx.x;
    const int w = tid >> 6, lane = tid & 63;
    const int lq = lane & 31, hi = lane >> 5;
    const int hi8 = hi * 8, hi4 = hi * 4;
    const int h = blockIdx.y, b = blockIdx.z;
    const int kvh = h >> 2;
    const unsigned short* kb = qkv + (size_t)(b * S_LEN) * QKV_N + KOFF + kvh * D_K;
    const unsigned short* vb = qkv + (size_t)(b * S_LEN) * QKV_N + VOFF + kvh * D_K;

    // causal balance: co-resident blocks (ids 256 apart) differ in b -> flip qt
    const int qt = b ? 7 - (int)blockIdx.x : (int)blockIdx.x;   // 0..7
    const int nt = 2 * qt + 2;
    const int qw0 = qt * 128 + w * 32;   // this wave's first q-row
    const int qg = qw0 + lq;             // this lane's q-row

    short8 aq[4];   // Q[qg][d]: d = hi*8 + {0..7} + 16*step
    {
        const unsigned short* qp = qkv + (size_t)(b * S_LEN + qg) * QKV_N + h * D_K + hi8;
#pragma unroll
        for (int st = 0; st < 4; st++) aq[st] = *(const short8*)(qp + st * 16);
    }
    f32x16 oacc[2];   // O^T: col=q(lane), row=d=crow(r,hi)+32*dt
#pragma unroll
    for (int dt = 0; dt < 2; dt++)
#pragma unroll
        for (int r = 0; r < 16; r++) oacc[dt][r] = 0.f;
    float m = -1e30f, l = 0.f;

    Pre pre;
    issue_pre(kb, vb, 0, tid, pre);
    for (int t = 0; t < nt; t++) {
        __syncthreads();                       // prev compute done; LDS free
        commit_pre(Ks, Vt, tid, pre);          // regs -> LDS
        __syncthreads();                       // staging visible
        if (t + 1 < nt) issue_pre(kb, vb, (t + 1) * 64, tid, pre);  // overlap
        const int t64 = t * 64;
        if (t64 > qw0 + 31) continue;          // wave done; keep doing barriers

        // ---- S^T = K * Q^T  (rows k, cols q=lane) ----
        f32x16 s0, s1;
#pragma unroll
        for (int r = 0; r < 16; r++) { s0[r] = 0.f; s1[r] = 0.f; }
        __builtin_amdgcn_s_setprio(1);
#pragma unroll
        for (int st = 0; st < 4; st++) {
            short8 k0 = *(const short8*)&Ks[lq * AST + st * 16 + hi8];
            short8 k1 = *(const short8*)&Ks[(32 + lq) * AST + st * 16 + hi8];
            s0 = __builtin_amdgcn_mfma_f32_32x32x16_bf16(k0, aq[st], s0, 0, 0, 0);
            s1 = __builtin_amdgcn_mfma_f32_32x32x16_bf16(k1, aq[st], s1, 0, 0, 0);
        }
        __builtin_amdgcn_s_setprio(0);
        float px[32];   // idx = kh*16 + r; k_local = (r&3)+8*(r>>2)+4*hi+32*kh
#pragma unroll
        for (int r = 0; r < 16; r++) { px[r] = s0[r]; px[16 + r] = s1[r]; }
        if (t64 + 63 > qw0) {   // diag tile: causal mask
#pragma unroll
            for (int kh = 0; kh < 2; kh++)
#pragma unroll
                for (int r = 0; r < 16; r++) {
                    int kg = t64 + kh * 32 + ((r & 3) + 8 * (r >> 2)) + hi4;
                    if (kg > qg) px[kh * 16 + r] = -1e30f;
                }
        }
        // ---- row max: in-lane tree + one permlane pair-exchange ----
        float tm[16];
#pragma unroll
        for (int i = 0; i < 16; i++) tm[i] = fmaxf(px[i], px[i + 16]);
#pragma unroll
        for (int i = 0; i < 8; i++) tm[i] = fmaxf(tm[i], tm[i + 8]);
#pragma unroll
        for (int i = 0; i < 4; i++) tm[i] = fmaxf(tm[i], tm[i + 4]);
        float lmax = fmaxf(fmaxf(tm[0], tm[1]), fmaxf(tm[2], tm[3]));
        union { float f; unsigned int u; } mb{lmax};
        auto rr = __builtin_amdgcn_permlane32_swap((int)mb.u, (int)mb.u, false, false);
        union { unsigned int u; float f; } ra, rb;
        ra.u = (unsigned int)rr[0];
        rb.u = (unsigned int)rr[1];
        float mn = fmaxf(m, fmaxf(ra.f, rb.f));
        // ---- T13 defer-max: skip rescale when growth <= THR (wave-uniform) ----
        if (!__all(mn - m <= RESCALE_THR)) {
            float corr = EXP2F(m - mn);
            m = mn;
            l *= corr;
#pragma unroll
            for (int dt = 0; dt < 2; dt++)
#pragma unroll
                for (int r = 0; r < 16; r++) oacc[dt][r] *= corr;
        }
        // ---- p = exp2(s - m); truncate to bf16 for P/l consistency ----
        float p[32], pm[32];
#pragma unroll
        for (int i = 0; i < 32; i++) {
            p[i] = EXP2F(px[i] - m);
            union { float f; unsigned int u; } pu{p[i]};
            pu.u &= 0xFFFF0000u;
            pm[i] = pu.f;
        }
        // ---- row sum: in-lane tree + permlane pair-exchange ----
        float ts[16];
#pragma unroll
        for (int i = 0; i < 16; i++) ts[i] = pm[i] + pm[i + 16];
#pragma unroll
        for (int i = 0; i < 8; i++) ts[i] = ts[i] + ts[i + 8];
#pragma unroll
        for (int i = 0; i < 4; i++) ts[i] = ts[i] + ts[i + 4];
        float lsum = (ts[0] + ts[1]) + (ts[2] + ts[3]);
        union { float f; unsigned int u; } sb{lsum};
        auto rr2 = __builtin_amdgcn_permlane32_swap((int)sb.u, (int)sb.u, false, false);
        union { unsigned int u; float f; } sa2, sb2;
        sa2.u = (unsigned int)rr2[0];
        sb2.u = (unsigned int)rr2[1];
        l = l + (sa2.f + sb2.f);
        // ---- pack P -> bf16 B-fragments (P^T: col=q, k = hi*8+e+16*sl) ----
        short8 pf[4];
#pragma unroll
        for (int kh = 0; kh < 2; kh++)
#pragma unroll
            for (int s = 0; s < 2; s++) {
                int base = kh * 16 + 8 * s;
                unsigned int a01 = permpack(p[base + 1], p[base + 0]);
                unsigned int a23 = permpack(p[base + 3], p[base + 2]);
                unsigned int a45 = permpack(p[base + 5], p[base + 4]);
                unsigned int a67 = permpack(p[base + 7], p[base + 6]);
                auto r02 = __builtin_amdgcn_permlane32_swap((int)a01, (int)a45, false, false);
                auto r13 = __builtin_amdgcn_permlane32_swap((int)a23, (int)a67, false, false);
                union { unsigned int wd[4]; short8 v; } pk;
                pk.wd[0] = (unsigned int)r02[0];
                pk.wd[1] = (unsigned int)r13[0];
                pk.wd[2] = (unsigned int)r02[1];
                pk.wd[3] = (unsigned int)r13[1];
                pf[kh * 2 + s] = pk.v;
            }
        // ---- O^T += V^T * P^T ----
        __builtin_amdgcn_s_setprio(1);
#pragma unroll
        for (int dt = 0; dt < 2; dt++)
#pragma unroll
            for (int sl = 0; sl < 4; sl++) {
                short8 va = *(const short8*)&Vt[(dt * 32 + lq) * AST + sl * 16 + hi8];
                oacc[dt] = __builtin_amdgcn_mfma_f32_32x32x16_bf16(va, pf[sl], oacc[dt], 0, 0, 0);
            }
        __builtin_amdgcn_s_setprio(0);
    }
    // ---- epilogue: O^T -> per-wave LDS transpose -> coalesced stores ----
    __syncthreads();                           // all waves done with Ks/Vt
    float inv = 1.f / l;
    unsigned short* Os = SM + w * 32 * AST;    // per-wave 32x72 region
#pragma unroll
    for (int dt = 0; dt < 2; dt++)
#pragma unroll
        for (int j = 0; j < 8; j++) {          // r = 2j, 2j+1 -> d, d+1
            int d = dt * 32 + ((2 * j) & 3) + 8 * (j >> 1) + hi4;
            unsigned int pk = (unsigned int)f2bf(oacc[dt][2 * j] * inv)
                            | ((unsigned int)f2bf(oacc[dt][2 * j + 1] * inv) << 16);
            *(unsigned int*)&Os[lq * AST + d] = pk;
        }
    __syncthreads();
#pragma unroll
    for (int j = 0; j < 4; j++) {
        int row = j * 8 + (lane >> 3);
        short8 v = *(const short8*)&Os[row * AST + (lane & 7) * 8];
        int qrow = b * S_LEN + qw0 + row;
        *(short8*)&obf[(size_t)qrow * D_MODEL + h * D_K + (lane & 7) * 8] = v;
    }
}

extern "C" void kernel_launch(void* const* d_in, const int* in_sizes, int n_in,
                              void* d_out, int out_size, void* d_ws, size_t ws_size,
                              hipStream_t stream) {
    const float* x  = (const float*)d_in[0];
    const float* Wq = (const float*)d_in[1];
    const float* bq = (const float*)d_in[2];
    const float* Wk = (const float*)d_in[3];
    const float* bk = (const float*)d_in[4];
    const float* Wv = (const float*)d_in[5];
    const float* bv = (const float*)d_in[6];
    const float* Wo = (const float*)d_in[7];
    const float* bo = (const float*)d_in[8];
    float* out = (float*)d_out;

    // ws (bf16 elems): xbf/obf 8MB | WtQKV 12MB | WtO 8MB | qkv 12MB | bias 12KB
    //                 | rope table 256KB  = ~40.3MB
    unsigned short* xbf   = (unsigned short*)d_ws;                       // [2048][2048]
    unsigned short* WtQKV = xbf + (size_t)M_ROWS * D_MODEL;              // [3072][2048]
    unsigned short* WtO   = WtQKV + (size_t)QKV_N * D_MODEL;             // [2048][2048]
    unsigned short* qkv   = WtO + (size_t)D_MODEL * D_MODEL;             // [2048][3072]
    float* bias_qkv       = (float*)(qkv + (size_t)M_ROWS * QKV_N);      // [3072]
    float2* rtab          = (float2*)(bias_qkv + QKV_N);                 // [1024][32]
    unsigned short* obf   = xbf;  // xbf consumed by QKV GEMM before attn writes

    dim3 gb(256);

    cast_bf_kernel<<<(M_ROWS * D_MODEL / 4 + 255) / 256, gb, 0, stream>>>(x, xbf, M_ROWS * D_MODEL / 4);
    wprep_kernel<<<dim3(32, 32, 4), gb, 0, stream>>>(Wq, Wk, Wv, Wo, WtQKV, WtO);
    prep_small_kernel<<<(QKV_N + TAB_N + 255) / 256, gb, 0, stream>>>(bq, bk, bv, bias_qkv, rtab);
    // fused QKV projection + RoPE (bf16 out): 48 x 16 = 768 blocks
    gemm_bf16_kernel<unsigned short, true><<<dim3(QKV_N / 64, M_ROWS / 128), gb, 0, stream>>>(
        xbf, WtQKV, bias_qkv, rtab, qkv, M_ROWS, QKV_N, D_MODEL);
    // attention: 128-row q-tile per block, swapped-operand 32x32 MFMA, 512 blocks
    attn_mfma_kernel<<<dim3(8, N_HEAD, B_SZ), gb, 0, stream>>>(qkv, obf);
    // O projection (fp32 out): 32 x 16 = 512 blocks
    gemm_bf16_kernel<float, false><<<dim3(D_MODEL / 64, M_ROWS / 128), gb, 0, stream>>>(
        obf, WtO, bo, nullptr, out, M_ROWS, D_MODEL, D_MODEL);
}

// Round 8
// 218.869 us; speedup vs baseline: 1.1240x; 1.0084x over previous
//
#include <hip/hip_runtime.h>
#include <hip/hip_bf16.h>

#define D_MODEL 2048
#define N_HEAD 32
#define N_KV_HEAD 8
#define N_REP 4
#define D_K 64
#define S_LEN 1024
#define B_SZ 2
#define M_ROWS (B_SZ * S_LEN)      // 2048
#define KV_DIM (N_KV_HEAD * D_K)   // 512
#define QKV_N 3072                 // 2048 q | 512 k | 512 v
#define KOFF 2048
#define VOFF 2560
#define LOG2E 1.44269504088896f
#define TAB_N (S_LEN * 32)         // rope cos/sin table entries

typedef __attribute__((ext_vector_type(8))) short short8;   // 8 bf16 (4 VGPRs)
typedef __attribute__((ext_vector_type(4))) float f32x4;
typedef __attribute__((ext_vector_type(16))) float f32x16;

#define EXP2F(x) __builtin_amdgcn_exp2f(x)   // v_exp_f32 (2^x native)

__device__ inline unsigned short f2bf(float f) {  // RNE fp32 -> bf16 bits
    union { float f; unsigned int u; } x{f};
    unsigned int r = x.u + 0x7fffu + ((x.u >> 16) & 1u);
    return (unsigned short)(r >> 16);
}
__device__ inline float bf2f(unsigned short b) {
    union { unsigned int u; float f; } x; x.u = ((unsigned int)b) << 16; return x.f;
}
__device__ inline void store_c(float* p, float v) { *p = v; }
__device__ inline void store_c(unsigned short* p, float v) { *p = f2bf(v); }

// async 16B global -> LDS (global_load_lds_dwordx4)
__device__ inline void load_lds16(const unsigned short* g, unsigned short* l) {
    __builtin_amdgcn_global_load_lds(
        (const __attribute__((address_space(1))) unsigned int*)g,
        (__attribute__((address_space(3))) unsigned int*)l, 16, 0, 0);
}

// pack two fp32 -> one u32 of 2 bf16 (truncation) via v_perm_b32
__device__ __forceinline__ unsigned int permpack(float hi_f, float lo_f) {
    union { float f; unsigned int u; } a{hi_f}, b{lo_f};
    return __builtin_amdgcn_perm(a.u, b.u, 0x07060302u);
}

// ------- fused prep: z=0..3 weight transpose+cast, z=4..5 x fp32->bf16 cast ----
__global__ __launch_bounds__(256) void prep_kernel(
        const float* __restrict__ x,
        const float* __restrict__ Wq_, const float* __restrict__ Wk_,
        const float* __restrict__ Wv_, const float* __restrict__ Wo_,
        unsigned short* __restrict__ xbf,
        unsigned short* __restrict__ WtQKV, unsigned short* __restrict__ WtO) {
    const int z = blockIdx.z;
    if (z >= 4) {
        // cast x (2048x2048 fp32) -> xbf bf16; 2 float4 per thread
        int idx = ((z - 4) * 1024 + blockIdx.y * 32 + blockIdx.x) * 256 + threadIdx.x;
#pragma unroll
        for (int half = 0; half < 2; half++) {
            int i = idx + half * 524288;
            float4 v = ((const float4*)x)[i];
            unsigned int lo = (unsigned int)f2bf(v.x) | ((unsigned int)f2bf(v.y) << 16);
            unsigned int hi = (unsigned int)f2bf(v.z) | ((unsigned int)f2bf(v.w) << 16);
            ((uint2*)xbf)[i] = make_uint2(lo, hi);
        }
        return;
    }
    const float* src; unsigned short* dst; int N;
    switch (z) {
        case 0: src = Wq_; dst = WtQKV; N = D_MODEL; break;
        case 1: src = Wk_; dst = WtQKV + (size_t)KOFF * D_MODEL; N = KV_DIM; break;
        case 2: src = Wv_; dst = WtQKV + (size_t)VOFF * D_MODEL; N = KV_DIM; break;
        default: src = Wo_; dst = WtO; N = D_MODEL; break;
    }
    int n0 = blockIdx.x * 64;
    if (n0 >= N) return;
    int k0 = blockIdx.y * 64;
    int t = threadIdx.x;
    int n = n0 + (t >> 2);
    int ks = k0 + (t & 3) * 16;
    unsigned int pk[8];
#pragma unroll
    for (int i = 0; i < 8; i++) {
        float a = src[(size_t)(ks + 2 * i) * N + n];
        float b = src[(size_t)(ks + 2 * i + 1) * N + n];
        pk[i] = (unsigned int)f2bf(a) | ((unsigned int)f2bf(b) << 16);
    }
    uint4* d = (uint4*)&dst[(size_t)n * D_MODEL + ks];
    d[0] = make_uint4(pk[0], pk[1], pk[2], pk[3]);
    d[1] = make_uint4(pk[4], pk[5], pk[6], pk[7]);
}

// -------- concat bias q|k|v (fp32) + rope cos/sin table [1024][32] ------------
__global__ void prep_small_kernel(const float* __restrict__ bq, const float* __restrict__ bk,
                                  const float* __restrict__ bv, float* __restrict__ dst,
                                  float2* __restrict__ tab) {
    int i = blockIdx.x * blockDim.x + threadIdx.x;
    if (i < QKV_N) {
        dst[i] = (i < KOFF) ? bq[i] : (i < VOFF) ? bk[i - KOFF] : bv[i - VOFF];
    }
    int j = i - QKV_N;
    if (j >= 0 && j < TAB_N) {
        int s = j >> 5, p = j & 31;
        float invf = EXP2F((float)p * -0.41524101186f);  // theta^(-2p/64)
        float ang = (float)s * invf;
        tab[j] = make_float2(__cosf(ang), __sinf(ang));
    }
}

// ---------------- bf16 GEMM: C[M,N] = A[M,K] * Bt[N,K]^T + bias ------
// BM=128, BN=64, BK=64, 256 thr = 4 waves (2x2); wave = 64x32 (4x2 16x16x32).
// (BK=128 trial: barrier savings cancelled by 4.7M LDS bank conflicts — reverted.)
// ROPE=true (QKV projection): fused rotary embedding in the epilogue. The pair
// partner (col^1) lives in lane^1 (cols split on lr bit0, same quad); cos/sin
// from the precomputed [1024][32] table (L2-resident). q cols also scaled by
// 0.125*log2e for the exp2-based softmax.
template <typename TC, bool ROPE>
__global__ __launch_bounds__(256) void gemm_bf16_kernel(
        const unsigned short* __restrict__ A,   // [M][K] bf16
        const unsigned short* __restrict__ Bt,  // [N][K] bf16
        const float* __restrict__ bias,
        const float2* __restrict__ rtab,
        TC* __restrict__ C, int M, int N, int K) {
    __shared__ unsigned short As[128 * 64];
    __shared__ unsigned short Bs[64 * 64];
    const int tid = threadIdx.x, lane = tid & 63;
    const int w = tid >> 6, wm = w >> 1, wn = w & 1;
    const int quad = lane >> 4, lr = lane & 15;
    const int bm = blockIdx.y * 128, bn = blockIdx.x * 64;

    f32x4 acc[4][2];
#pragma unroll
    for (int i = 0; i < 4; i++)
#pragma unroll
        for (int j = 0; j < 2; j++) acc[i][j] = (f32x4){0.f, 0.f, 0.f, 0.f};

    for (int k0 = 0; k0 < K; k0 += 64) {
        __syncthreads();
#pragma unroll
        for (int it = 0; it < 4; it++) {
            int slot = it * 256 + tid;
            int row = slot >> 3;
            int qc = (slot & 7) ^ (row & 7);
            load_lds16(A + (size_t)(bm + row) * K + k0 + qc * 8, &As[slot * 8]);
        }
#pragma unroll
        for (int it = 0; it < 2; it++) {
            int slot = it * 256 + tid;
            int row = slot >> 3;
            int qc = (slot & 7) ^ (row & 7);
            load_lds16(Bt + (size_t)(bn + row) * K + k0 + qc * 8, &Bs[slot * 8]);
        }
        __syncthreads();
#pragma unroll
        for (int ks = 0; ks < 2; ks++) {
            short8 af[4], bf[2];
#pragma unroll
            for (int i = 0; i < 4; i++) {
                int row = wm * 64 + i * 16 + lr;
                af[i] = *(const short8*)&As[(row * 8 + ((ks * 4 + quad) ^ (lr & 7))) * 8];
            }
#pragma unroll
            for (int j = 0; j < 2; j++) {
                int row = wn * 32 + j * 16 + lr;
                bf[j] = *(const short8*)&Bs[(row * 8 + ((ks * 4 + quad) ^ (lr & 7))) * 8];
            }
#pragma unroll
            for (int i = 0; i < 4; i++)
#pragma unroll
                for (int j = 0; j < 2; j++)
                    acc[i][j] = __builtin_amdgcn_mfma_f32_16x16x32_bf16(af[i], bf[j], acc[i][j], 0, 0, 0);
        }
    }
#pragma unroll
    for (int i = 0; i < 4; i++) {
#pragma unroll
        for (int j = 0; j < 2; j++) {
            int col = bn + wn * 32 + j * 16 + lr;
            int row0 = bm + wm * 64 + i * 16 + quad * 4;
            float bj = bias[col];
            if constexpr (ROPE) {
                // col class is uniform across the shfl pair (boundaries % 64 == 0)
                bool isv = col >= VOFF;
                bool isq = col < KOFF;
                int ip = (col & 63) >> 1;
                bool even = !(lr & 1);
#pragma unroll
                for (int r = 0; r < 4; r++) {
                    float v = acc[i][j][r] + bj;
                    float pv = __shfl_xor(v, 1);     // partner col^1 (lane^1)
                    float outv = v;
                    if (!isv) {
                        int s = (row0 + r) & (S_LEN - 1);
                        float2 cs = rtab[s * 32 + ip];
                        outv = v * cs.x + (even ? -pv : pv) * cs.y;
                        if (isq) outv *= 0.125f * LOG2E;
                    }
                    store_c(&C[(size_t)(row0 + r) * N + col], outv);
                }
            } else {
#pragma unroll
                for (int r = 0; r < 4; r++)
                    store_c(&C[(size_t)(row0 + r) * N + col], acc[i][j][r] + bj);
            }
        }
    }
}

// ---------------- MFMA flash attention: swapped-operand 32x32, in-reg softmax --
// Block = 256 thr = 4 waves; each wave owns 32 q-rows (block = 128-row q-tile).
// S^T = K*Q^T via mfma_32x32x16 -> lane holds one q-row's 32 scores per kh-half;
// softmax fully in registers (tree reduce + permlane32_swap, zero LDS ops);
// P packed to bf16 in-reg; O^T = V^T*P^T so the online rescale is lane-local.
// K/V LDS double-buffered: ONE barrier per KV tile (compute buf[t&1] ->
// commit buf[t&1^1] -> barrier); a wave's commit overlaps other waves' compute.
// T5 setprio around MFMA clusters; T13 defer-max (THR=8 log2) skips O-rescale.
#define AST 72
#define RESCALE_THR 8.0f
struct Pre { uint4 k0, k1, v0, v1; };

__device__ __forceinline__ void issue_pre(const unsigned short* kb,
                                          const unsigned short* vb,
                                          int j0, int tid, Pre& p) {
    int f0 = tid, f1 = tid + 256;
    p.k0 = *(const uint4*)(kb + (size_t)(j0 + (f0 >> 3)) * QKV_N + (f0 & 7) * 8);
    p.k1 = *(const uint4*)(kb + (size_t)(j0 + (f1 >> 3)) * QKV_N + (f1 & 7) * 8);
    int kp = tid & 31, dg = tid >> 5;
    p.v0 = *(const uint4*)(vb + (size_t)(j0 + 2 * kp) * QKV_N + dg * 8);
    p.v1 = *(const uint4*)(vb + (size_t)(j0 + 2 * kp + 1) * QKV_N + dg * 8);
}
__device__ __forceinline__ void commit_pre(unsigned short* Ks, unsigned short* Vt,
                                           int tid, const Pre& p) {
    int f0 = tid, f1 = tid + 256;
    *(uint4*)&Ks[(f0 >> 3) * AST + (f0 & 7) * 8] = p.k0;
    *(uint4*)&Ks[(f1 >> 3) * AST + (f1 & 7) * 8] = p.k1;
    int kp = tid & 31, dg = tid >> 5;
    const unsigned short* ta = (const unsigned short*)&p.v0;
    const unsigned short* tb = (const unsigned short*)&p.v1;
#pragma unroll
    for (int i = 0; i < 8; i++) {
        unsigned int pk = (unsigned int)ta[i] | ((unsigned int)tb[i] << 16);
        *(unsigned int*)&Vt[(dg * 8 + i) * AST + 2 * kp] = pk;
    }
}

__global__ __launch_bounds__(256) void attn_mfma_kernel(
        const unsigned short* __restrict__ qkv,   // [M_ROWS][QKV_N] bf16
        unsigned short* __restrict__ obf) {       // [M_ROWS][D_MODEL] bf16
    __shared__ unsigned short SM[4 * 64 * AST];   // {Ks|Vt} x2 (buf0 reused for O)
    const int tid = threadIdx.x;
    const int w = tid >> 6, lane = tid & 63;
    const int lq = lane & 31, hi = lane >> 5;
    const int hi8 = hi * 8, hi4 = hi * 4;
    const int h = blockIdx.y, b = blockIdx.z;
    const int kvh = h >> 2;
    const unsigned short* kb = qkv + (size_t)(b * S_LEN) * QKV_N + KOFF + kvh * D_K;
    const unsigned short* vb = qkv + (size_t)(b * S_LEN) * QKV_N + VOFF + kvh * D_K;

    // causal balance: co-resident blocks (ids 256 apart) differ in b -> flip qt
    const int qt = b ? 7 - (int)blockIdx.x : (int)blockIdx.x;   // 0..7
    const int nt = 2 * qt + 2;
    const int qw0 = qt * 128 + w * 32;   // this wave's first q-row
    const int qg = qw0 + lq;             // this lane's q-row

    short8 aq[4];   // Q[qg][d]: d = hi*8 + {0..7} + 16*step
    {
        const unsigned short* qp = qkv + (size_t)(b * S_LEN + qg) * QKV_N + h * D_K + hi8;
#pragma unroll
        for (int st = 0; st < 4; st++) aq[st] = *(const short8*)(qp + st * 16);
    }
    f32x16 oacc[2];   // O^T: col=q(lane), row=d=crow(r,hi)+32*dt
#pragma unroll
    for (int dt = 0; dt < 2; dt++)
#pragma unroll
        for (int r = 0; r < 16; r++) oacc[dt][r] = 0.f;
    float m = -1e30f, l = 0.f;

    Pre pre;
    issue_pre(kb, vb, 0, tid, pre);
    commit_pre(SM, SM + 64 * AST, tid, pre);           // tile 0 -> buf0
    if (nt > 1) issue_pre(kb, vb, 64, tid, pre);       // tile 1 -> regs
    __syncthreads();                                   // buf0 visible

    for (int t = 0; t < nt; t++) {
        const int par = t & 1;
        unsigned short* Ks = SM + par * (2 * 64 * AST);
        unsigned short* Vt = Ks + 64 * AST;
        const int t64 = t * 64;
        if (t64 <= qw0 + 31) {
            // ---- S^T = K * Q^T  (rows k, cols q=lane) ----
            f32x16 s0, s1;
#pragma unroll
            for (int r = 0; r < 16; r++) { s0[r] = 0.f; s1[r] = 0.f; }
            __builtin_amdgcn_s_setprio(1);
#pragma unroll
            for (int st = 0; st < 4; st++) {
                short8 k0 = *(const short8*)&Ks[lq * AST + st * 16 + hi8];
                short8 k1 = *(const short8*)&Ks[(32 + lq) * AST + st * 16 + hi8];
                s0 = __builtin_amdgcn_mfma_f32_32x32x16_bf16(k0, aq[st], s0, 0, 0, 0);
                s1 = __builtin_amdgcn_mfma_f32_32x32x16_bf16(k1, aq[st], s1, 0, 0, 0);
            }
            __builtin_amdgcn_s_setprio(0);
            float px[32];   // idx = kh*16 + r; k_local = (r&3)+8*(r>>2)+4*hi+32*kh
#pragma unroll
            for (int r = 0; r < 16; r++) { px[r] = s0[r]; px[16 + r] = s1[r]; }
            if (t64 + 63 > qw0) {   // diag tile: causal mask
#pragma unroll
                for (int kh = 0; kh < 2; kh++)
#pragma unroll
                    for (int r = 0; r < 16; r++) {
                        int kg = t64 + kh * 32 + ((r & 3) + 8 * (r >> 2)) + hi4;
                        if (kg > qg) px[kh * 16 + r] = -1e30f;
                    }
            }
            // ---- row max: in-lane tree + one permlane pair-exchange ----
            float tm[16];
#pragma unroll
            for (int i = 0; i < 16; i++) tm[i] = fmaxf(px[i], px[i + 16]);
#pragma unroll
            for (int i = 0; i < 8; i++) tm[i] = fmaxf(tm[i], tm[i + 8]);
#pragma unroll
            for (int i = 0; i < 4; i++) tm[i] = fmaxf(tm[i], tm[i + 4]);
            float lmax = fmaxf(fmaxf(tm[0], tm[1]), fmaxf(tm[2], tm[3]));
            union { float f; unsigned int u; } mb{lmax};
            auto rr = __builtin_amdgcn_permlane32_swap((int)mb.u, (int)mb.u, false, false);
            union { unsigned int u; float f; } ra, rb;
            ra.u = (unsigned int)rr[0];
            rb.u = (unsigned int)rr[1];
            float mn = fmaxf(m, fmaxf(ra.f, rb.f));
            // ---- T13 defer-max: skip rescale when growth <= THR (wave-uniform) ----
            if (!__all(mn - m <= RESCALE_THR)) {
                float corr = EXP2F(m - mn);
                m = mn;
                l *= corr;
#pragma unroll
                for (int dt = 0; dt < 2; dt++)
#pragma unroll
                    for (int r = 0; r < 16; r++) oacc[dt][r] *= corr;
            }
            // ---- p = exp2(s - m); truncate to bf16 for P/l consistency ----
            float p[32], pm[32];
#pragma unroll
            for (int i = 0; i < 32; i++) {
                p[i] = EXP2F(px[i] - m);
                union { float f; unsigned int u; } pu{p[i]};
                pu.u &= 0xFFFF0000u;
                pm[i] = pu.f;
            }
            // ---- row sum: in-lane tree + permlane pair-exchange ----
            float ts[16];
#pragma unroll
            for (int i = 0; i < 16; i++) ts[i] = pm[i] + pm[i + 16];
#pragma unroll
            for (int i = 0; i < 8; i++) ts[i] = ts[i] + ts[i + 8];
#pragma unroll
            for (int i = 0; i < 4; i++) ts[i] = ts[i] + ts[i + 4];
            float lsum = (ts[0] + ts[1]) + (ts[2] + ts[3]);
            union { float f; unsigned int u; } sb{lsum};
            auto rr2 = __builtin_amdgcn_permlane32_swap((int)sb.u, (int)sb.u, false, false);
            union { unsigned int u; float f; } sa2, sb2;
            sa2.u = (unsigned int)rr2[0];
            sb2.u = (unsigned int)rr2[1];
            l = l + (sa2.f + sb2.f);
            // ---- pack P -> bf16 B-fragments (P^T: col=q, k = hi*8+e+16*sl) ----
            short8 pf[4];
#pragma unroll
            for (int kh = 0; kh < 2; kh++)
#pragma unroll
                for (int s = 0; s < 2; s++) {
                    int base = kh * 16 + 8 * s;
                    unsigned int a01 = permpack(p[base + 1], p[base + 0]);
                    unsigned int a23 = permpack(p[base + 3], p[base + 2]);
                    unsigned int a45 = permpack(p[base + 5], p[base + 4]);
                    unsigned int a67 = permpack(p[base + 7], p[base + 6]);
                    auto r02 = __builtin_amdgcn_permlane32_swap((int)a01, (int)a45, false, false);
                    auto r13 = __builtin_amdgcn_permlane32_swap((int)a23, (int)a67, false, false);
                    union { unsigned int wd[4]; short8 v; } pk;
                    pk.wd[0] = (unsigned int)r02[0];
                    pk.wd[1] = (unsigned int)r13[0];
                    pk.wd[2] = (unsigned int)r02[1];
                    pk.wd[3] = (unsigned int)r13[1];
                    pf[kh * 2 + s] = pk.v;
                }
            // ---- O^T += V^T * P^T ----
            __builtin_amdgcn_s_setprio(1);
#pragma unroll
            for (int dt = 0; dt < 2; dt++)
#pragma unroll
                for (int sl = 0; sl < 4; sl++) {
                    short8 va = *(const short8*)&Vt[(dt * 32 + lq) * AST + sl * 16 + hi8];
                    oacc[dt] = __builtin_amdgcn_mfma_f32_32x32x16_bf16(va, pf[sl], oacc[dt], 0, 0, 0);
                }
            __builtin_amdgcn_s_setprio(0);
        }
        // stage tile t+1 into the other buffer; issue tile t+2 global loads
        if (t + 1 < nt) {
            unsigned short* Kn = SM + (par ^ 1) * (2 * 64 * AST);
            commit_pre(Kn, Kn + 64 * AST, tid, pre);
            if (t + 2 < nt) issue_pre(kb, vb, (t + 2) * 64, tid, pre);
        }
        __syncthreads();   // commit visible for t+1; also guards WAR for t+2
    }
    // ---- epilogue: O^T -> per-wave LDS transpose -> coalesced stores ----
    // (loop-end barrier already separates last compute from these writes)
    float inv = 1.f / l;
    unsigned short* Os = SM + w * 32 * AST;    // per-wave 32x72 region (buf0)
#pragma unroll
    for (int dt = 0; dt < 2; dt++)
#pragma unroll
        for (int j = 0; j < 8; j++) {          // r = 2j, 2j+1 -> d, d+1
            int d = dt * 32 + ((2 * j) & 3) + 8 * (j >> 1) + hi4;
            unsigned int pk = (unsigned int)f2bf(oacc[dt][2 * j] * inv)
                            | ((unsigned int)f2bf(oacc[dt][2 * j + 1] * inv) << 16);
            *(unsigned int*)&Os[lq * AST + d] = pk;
        }
    __syncthreads();
#pragma unroll
    for (int j = 0; j < 4; j++) {
        int row = j * 8 + (lane >> 3);
        short8 v = *(const short8*)&Os[row * AST + (lane & 7) * 8];
        int qrow = b * S_LEN + qw0 + row;
        *(short8*)&obf[(size_t)qrow * D_MODEL + h * D_K + (lane & 7) * 8] = v;
    }
}

extern "C" void kernel_launch(void* const* d_in, const int* in_sizes, int n_in,
                              void* d_out, int out_size, void* d_ws, size_t ws_size,
                              hipStream_t stream) {
    const float* x  = (const float*)d_in[0];
    const float* Wq = (const float*)d_in[1];
    const float* bq = (const float*)d_in[2];
    const float* Wk = (const float*)d_in[3];
    const float* bk = (const float*)d_in[4];
    const float* Wv = (const float*)d_in[5];
    const float* bv = (const float*)d_in[6];
    const float* Wo = (const float*)d_in[7];
    const float* bo = (const float*)d_in[8];
    float* out = (float*)d_out;

    // ws (bf16 elems): xbf/obf 8MB | WtQKV 12MB | WtO 8MB | qkv 12MB | bias 12KB
    //                 | rope table 256KB  = ~40.3MB
    unsigned short* xbf   = (unsigned short*)d_ws;                       // [2048][2048]
    unsigned short* WtQKV = xbf + (size_t)M_ROWS * D_MODEL;              // [3072][2048]
    unsigned short* WtO   = WtQKV + (size_t)QKV_N * D_MODEL;             // [2048][2048]
    unsigned short* qkv   = WtO + (size_t)D_MODEL * D_MODEL;             // [2048][3072]
    float* bias_qkv       = (float*)(qkv + (size_t)M_ROWS * QKV_N);      // [3072]
    float2* rtab          = (float2*)(bias_qkv + QKV_N);                 // [1024][32]
    unsigned short* obf   = xbf;  // xbf consumed by QKV GEMM before attn writes

    dim3 gb(256);

    // fused prep: weights transpose (z=0..3) + x cast (z=4..5)
    prep_kernel<<<dim3(32, 32, 6), gb, 0, stream>>>(x, Wq, Wk, Wv, Wo, xbf, WtQKV, WtO);
    prep_small_kernel<<<(QKV_N + TAB_N + 255) / 256, gb, 0, stream>>>(bq, bk, bv, bias_qkv, rtab);
    // fused QKV projection + RoPE (bf16 out): 48 x 16 = 768 blocks
    gemm_bf16_kernel<unsigned short, true><<<dim3(QKV_N / 64, M_ROWS / 128), gb, 0, stream>>>(
        xbf, WtQKV, bias_qkv, rtab, qkv, M_ROWS, QKV_N, D_MODEL);
    // attention: 128-row q-tile per block, dbuf K/V (1 barrier/tile), 512 blocks
    attn_mfma_kernel<<<dim3(8, N_HEAD, B_SZ), gb, 0, stream>>>(qkv, obf);
    // O projection (fp32 out): 32 x 16 = 512 blocks
    gemm_bf16_kernel<float, false><<<dim3(D_MODEL / 64, M_ROWS / 128), gb, 0, stream>>>(
        obf, WtO, bo, nullptr, out, M_ROWS, D_MODEL, D_MODEL);
}

// Round 9
// 214.364 us; speedup vs baseline: 1.1477x; 1.0210x over previous
//
#include <hip/hip_runtime.h>
#include <hip/hip_bf16.h>

#define D_MODEL 2048
#define N_HEAD 32
#define N_KV_HEAD 8
#define N_REP 4
#define D_K 64
#define S_LEN 1024
#define B_SZ 2
#define M_ROWS (B_SZ * S_LEN)      // 2048
#define KV_DIM (N_KV_HEAD * D_K)   // 512
#define QKV_N 3072                 // 2048 q | 512 k | 512 v
#define KOFF 2048
#define VOFF 2560
#define LOG2E 1.44269504088896f
#define TAB_N (S_LEN * 32)         // rope cos/sin table entries

typedef __attribute__((ext_vector_type(8))) short short8;   // 8 bf16 (4 VGPRs)
typedef __attribute__((ext_vector_type(4))) float f32x4;
typedef __attribute__((ext_vector_type(16))) float f32x16;

#define EXP2F(x) __builtin_amdgcn_exp2f(x)   // v_exp_f32 (2^x native)

__device__ inline unsigned short f2bf(float f) {  // RNE fp32 -> bf16 bits
    union { float f; unsigned int u; } x{f};
    unsigned int r = x.u + 0x7fffu + ((x.u >> 16) & 1u);
    return (unsigned short)(r >> 16);
}
__device__ inline float bf2f(unsigned short b) {
    union { unsigned int u; float f; } x; x.u = ((unsigned int)b) << 16; return x.f;
}
__device__ inline void store_c(float* p, float v) { *p = v; }
__device__ inline void store_c(unsigned short* p, float v) { *p = f2bf(v); }

// async 16B global -> LDS (global_load_lds_dwordx4)
__device__ inline void load_lds16(const unsigned short* g, unsigned short* l) {
    __builtin_amdgcn_global_load_lds(
        (const __attribute__((address_space(1))) unsigned int*)g,
        (__attribute__((address_space(3))) unsigned int*)l, 16, 0, 0);
}

// pack two fp32 -> one u32 of 2 bf16 (truncation) via v_perm_b32
__device__ __forceinline__ unsigned int permpack(float hi_f, float lo_f) {
    union { float f; unsigned int u; } a{hi_f}, b{lo_f};
    return __builtin_amdgcn_perm(a.u, b.u, 0x07060302u);
}

// ------- fused prep: z=0..3 weight transpose+cast, z=4..5 x cast, z=6 small ----
__global__ __launch_bounds__(256) void prep_kernel(
        const float* __restrict__ x,
        const float* __restrict__ Wq_, const float* __restrict__ Wk_,
        const float* __restrict__ Wv_, const float* __restrict__ Wo_,
        const float* __restrict__ bq, const float* __restrict__ bk,
        const float* __restrict__ bv,
        unsigned short* __restrict__ xbf,
        unsigned short* __restrict__ WtQKV, unsigned short* __restrict__ WtO,
        float* __restrict__ bias_qkv, float2* __restrict__ rtab) {
    const int z = blockIdx.z;
    if (z == 6) {
        // bias concat + rope cos/sin table
        int i = (blockIdx.y * 32 + blockIdx.x) * 256 + threadIdx.x;
        if (i < QKV_N) {
            bias_qkv[i] = (i < KOFF) ? bq[i] : (i < VOFF) ? bk[i - KOFF] : bv[i - VOFF];
        }
        int j = i - QKV_N;
        if (j >= 0 && j < TAB_N) {
            int s = j >> 5, p = j & 31;
            float invf = EXP2F((float)p * -0.41524101186f);  // theta^(-2p/64)
            float ang = (float)s * invf;
            rtab[j] = make_float2(__cosf(ang), __sinf(ang));
        }
        return;
    }
    if (z >= 4) {
        // cast x (2048x2048 fp32) -> xbf bf16; 2 float4 per thread
        int idx = ((z - 4) * 1024 + blockIdx.y * 32 + blockIdx.x) * 256 + threadIdx.x;
#pragma unroll
        for (int half = 0; half < 2; half++) {
            int i = idx + half * 524288;
            float4 v = ((const float4*)x)[i];
            unsigned int lo = (unsigned int)f2bf(v.x) | ((unsigned int)f2bf(v.y) << 16);
            unsigned int hi = (unsigned int)f2bf(v.z) | ((unsigned int)f2bf(v.w) << 16);
            ((uint2*)xbf)[i] = make_uint2(lo, hi);
        }
        return;
    }
    const float* src; unsigned short* dst; int N;
    switch (z) {
        case 0: src = Wq_; dst = WtQKV; N = D_MODEL; break;
        case 1: src = Wk_; dst = WtQKV + (size_t)KOFF * D_MODEL; N = KV_DIM; break;
        case 2: src = Wv_; dst = WtQKV + (size_t)VOFF * D_MODEL; N = KV_DIM; break;
        default: src = Wo_; dst = WtO; N = D_MODEL; break;
    }
    int n0 = blockIdx.x * 64;
    if (n0 >= N) return;
    int k0 = blockIdx.y * 64;
    int t = threadIdx.x;
    int n = n0 + (t >> 2);
    int ks = k0 + (t & 3) * 16;
    unsigned int pk[8];
#pragma unroll
    for (int i = 0; i < 8; i++) {
        float a = src[(size_t)(ks + 2 * i) * N + n];
        float b = src[(size_t)(ks + 2 * i + 1) * N + n];
        pk[i] = (unsigned int)f2bf(a) | ((unsigned int)f2bf(b) << 16);
    }
    uint4* d = (uint4*)&dst[(size_t)n * D_MODEL + ks];
    d[0] = make_uint4(pk[0], pk[1], pk[2], pk[3]);
    d[1] = make_uint4(pk[4], pk[5], pk[6], pk[7]);
}

// ---------------- bf16 GEMM: C[M,N] = A[M,K] * Bt[N,K]^T + bias ------
// BM=128, BN=64, BK=64, 256 thr = 4 waves (2x2); wave = 64x32 (4x2 16x16x32).
// T3 minimum-2-phase: LDS double-buffered; tile t+1's global_load_lds issued
// BEFORE computing tile t, ONE __syncthreads per K-step at the end. The
// pre-barrier vmcnt(0) drain then waits on loads that had the whole compute
// phase to land (vs cold-stall in the 1-phase structure). LDS 48 KB -> 3 blk/CU.
// ROPE=true (QKV projection): fused rotary embedding in the epilogue; cos/sin
// from the precomputed [1024][32] table; q cols scaled by 0.125*log2e.
template <typename TC, bool ROPE>
__global__ __launch_bounds__(256) void gemm_bf16_kernel(
        const unsigned short* __restrict__ A,   // [M][K] bf16
        const unsigned short* __restrict__ Bt,  // [N][K] bf16
        const float* __restrict__ bias,
        const float2* __restrict__ rtab,
        TC* __restrict__ C, int M, int N, int K) {
    __shared__ unsigned short As[2][128 * 64];
    __shared__ unsigned short Bs[2][64 * 64];
    const int tid = threadIdx.x, lane = tid & 63;
    const int w = tid >> 6, wm = w >> 1, wn = w & 1;
    const int quad = lane >> 4, lr = lane & 15;
    const int bm = blockIdx.y * 128, bn = blockIdx.x * 64;

    f32x4 acc[4][2];
#pragma unroll
    for (int i = 0; i < 4; i++)
#pragma unroll
        for (int j = 0; j < 2; j++) acc[i][j] = (f32x4){0.f, 0.f, 0.f, 0.f};

    auto stage = [&](int buf, int k0) {
#pragma unroll
        for (int it = 0; it < 4; it++) {
            int slot = it * 256 + tid;
            int row = slot >> 3;
            int qc = (slot & 7) ^ (row & 7);
            load_lds16(A + (size_t)(bm + row) * K + k0 + qc * 8, &As[buf][slot * 8]);
        }
#pragma unroll
        for (int it = 0; it < 2; it++) {
            int slot = it * 256 + tid;
            int row = slot >> 3;
            int qc = (slot & 7) ^ (row & 7);
            load_lds16(Bt + (size_t)(bn + row) * K + k0 + qc * 8, &Bs[buf][slot * 8]);
        }
    };

    stage(0, 0);
    __syncthreads();                       // tile 0 resident
    int cur = 0;
    for (int k0 = 0; k0 < K; k0 += 64) {
        if (k0 + 64 < K) stage(cur ^ 1, k0 + 64);   // prefetch overlaps compute
#pragma unroll
        for (int ks = 0; ks < 2; ks++) {
            short8 af[4], bf[2];
#pragma unroll
            for (int i = 0; i < 4; i++) {
                int row = wm * 64 + i * 16 + lr;
                af[i] = *(const short8*)&As[cur][(row * 8 + ((ks * 4 + quad) ^ (lr & 7))) * 8];
            }
#pragma unroll
            for (int j = 0; j < 2; j++) {
                int row = wn * 32 + j * 16 + lr;
                bf[j] = *(const short8*)&Bs[cur][(row * 8 + ((ks * 4 + quad) ^ (lr & 7))) * 8];
            }
#pragma unroll
            for (int i = 0; i < 4; i++)
#pragma unroll
                for (int j = 0; j < 2; j++)
                    acc[i][j] = __builtin_amdgcn_mfma_f32_16x16x32_bf16(af[i], bf[j], acc[i][j], 0, 0, 0);
        }
        __syncthreads();                   // drains prefetch; frees cur for t+2
        cur ^= 1;
    }
#pragma unroll
    for (int i = 0; i < 4; i++) {
#pragma unroll
        for (int j = 0; j < 2; j++) {
            int col = bn + wn * 32 + j * 16 + lr;
            int row0 = bm + wm * 64 + i * 16 + quad * 4;
            float bj = bias[col];
            if constexpr (ROPE) {
                // col class is uniform across the shfl pair (boundaries % 64 == 0)
                bool isv = col >= VOFF;
                bool isq = col < KOFF;
                int ip = (col & 63) >> 1;
                bool even = !(lr & 1);
#pragma unroll
                for (int r = 0; r < 4; r++) {
                    float v = acc[i][j][r] + bj;
                    float pv = __shfl_xor(v, 1);     // partner col^1 (lane^1)
                    float outv = v;
                    if (!isv) {
                        int s = (row0 + r) & (S_LEN - 1);
                        float2 cs = rtab[s * 32 + ip];
                        outv = v * cs.x + (even ? -pv : pv) * cs.y;
                        if (isq) outv *= 0.125f * LOG2E;
                    }
                    store_c(&C[(size_t)(row0 + r) * N + col], outv);
                }
            } else {
#pragma unroll
                for (int r = 0; r < 4; r++)
                    store_c(&C[(size_t)(row0 + r) * N + col], acc[i][j][r] + bj);
            }
        }
    }
}

// ---------------- MFMA flash attention: swapped-operand 32x32, in-reg softmax --
// Block = 256 thr = 4 waves; each wave owns 32 q-rows (block = 128-row q-tile).
// S^T = K*Q^T via mfma_32x32x16 -> lane holds one q-row's 32 scores per kh-half;
// softmax fully in registers (tree reduce + permlane32_swap, zero LDS ops);
// P packed to bf16 in-reg; O^T = V^T*P^T so the online rescale is lane-local.
// K/V LDS double-buffered: ONE barrier per KV tile (compute buf[t&1] ->
// commit buf[t&1^1] -> barrier); a wave's commit overlaps other waves' compute.
// T5 setprio around MFMA clusters; T13 defer-max (THR=8 log2) skips O-rescale.
#define AST 72
#define RESCALE_THR 8.0f
struct Pre { uint4 k0, k1, v0, v1; };

__device__ __forceinline__ void issue_pre(const unsigned short* kb,
                                          const unsigned short* vb,
                                          int j0, int tid, Pre& p) {
    int f0 = tid, f1 = tid + 256;
    p.k0 = *(const uint4*)(kb + (size_t)(j0 + (f0 >> 3)) * QKV_N + (f0 & 7) * 8);
    p.k1 = *(const uint4*)(kb + (size_t)(j0 + (f1 >> 3)) * QKV_N + (f1 & 7) * 8);
    int kp = tid & 31, dg = tid >> 5;
    p.v0 = *(const uint4*)(vb + (size_t)(j0 + 2 * kp) * QKV_N + dg * 8);
    p.v1 = *(const uint4*)(vb + (size_t)(j0 + 2 * kp + 1) * QKV_N + dg * 8);
}
__device__ __forceinline__ void commit_pre(unsigned short* Ks, unsigned short* Vt,
                                           int tid, const Pre& p) {
    int f0 = tid, f1 = tid + 256;
    *(uint4*)&Ks[(f0 >> 3) * AST + (f0 & 7) * 8] = p.k0;
    *(uint4*)&Ks[(f1 >> 3) * AST + (f1 & 7) * 8] = p.k1;
    int kp = tid & 31, dg = tid >> 5;
    const unsigned short* ta = (const unsigned short*)&p.v0;
    const unsigned short* tb = (const unsigned short*)&p.v1;
#pragma unroll
    for (int i = 0; i < 8; i++) {
        unsigned int pk = (unsigned int)ta[i] | ((unsigned int)tb[i] << 16);
        *(unsigned int*)&Vt[(dg * 8 + i) * AST + 2 * kp] = pk;
    }
}

__global__ __launch_bounds__(256) void attn_mfma_kernel(
        const unsigned short* __restrict__ qkv,   // [M_ROWS][QKV_N] bf16
        unsigned short* __restrict__ obf) {       // [M_ROWS][D_MODEL] bf16
    __shared__ unsigned short SM[4 * 64 * AST];   // {Ks|Vt} x2 (buf0 reused for O)
    const int tid = threadIdx.x;
    const int w = tid >> 6, lane = tid & 63;
    const int lq = lane & 31, hi = lane >> 5;
    const int hi8 = hi * 8, hi4 = hi * 4;
    const int h = blockIdx.y, b = blockIdx.z;
    const int kvh = h >> 2;
    const unsigned short* kb = qkv + (size_t)(b * S_LEN) * QKV_N + KOFF + kvh * D_K;
    const unsigned short* vb = qkv + (size_t)(b * S_LEN) * QKV_N + VOFF + kvh * D_K;

    // causal balance: co-resident blocks (ids 256 apart) differ in b -> flip qt
    const int qt = b ? 7 - (int)blockIdx.x : (int)blockIdx.x;   // 0..7
    const int nt = 2 * qt + 2;
    const int qw0 = qt * 128 + w * 32;   // this wave's first q-row
    const int qg = qw0 + lq;             // this lane's q-row

    short8 aq[4];   // Q[qg][d]: d = hi*8 + {0..7} + 16*step
    {
        const unsigned short* qp = qkv + (size_t)(b * S_LEN + qg) * QKV_N + h * D_K + hi8;
#pragma unroll
        for (int st = 0; st < 4; st++) aq[st] = *(const short8*)(qp + st * 16);
    }
    f32x16 oacc[2];   // O^T: col=q(lane), row=d=crow(r,hi)+32*dt
#pragma unroll
    for (int dt = 0; dt < 2; dt++)
#pragma unroll
        for (int r = 0; r < 16; r++) oacc[dt][r] = 0.f;
    float m = -1e30f, l = 0.f;

    Pre pre;
    issue_pre(kb, vb, 0, tid, pre);
    commit_pre(SM, SM + 64 * AST, tid, pre);           // tile 0 -> buf0
    if (nt > 1) issue_pre(kb, vb, 64, tid, pre);       // tile 1 -> regs
    __syncthreads();                                   // buf0 visible

    for (int t = 0; t < nt; t++) {
        const int par = t & 1;
        unsigned short* Ks = SM + par * (2 * 64 * AST);
        unsigned short* Vt = Ks + 64 * AST;
        const int t64 = t * 64;
        if (t64 <= qw0 + 31) {
            // ---- S^T = K * Q^T  (rows k, cols q=lane) ----
            f32x16 s0, s1;
#pragma unroll
            for (int r = 0; r < 16; r++) { s0[r] = 0.f; s1[r] = 0.f; }
            __builtin_amdgcn_s_setprio(1);
#pragma unroll
            for (int st = 0; st < 4; st++) {
                short8 k0 = *(const short8*)&Ks[lq * AST + st * 16 + hi8];
                short8 k1 = *(const short8*)&Ks[(32 + lq) * AST + st * 16 + hi8];
                s0 = __builtin_amdgcn_mfma_f32_32x32x16_bf16(k0, aq[st], s0, 0, 0, 0);
                s1 = __builtin_amdgcn_mfma_f32_32x32x16_bf16(k1, aq[st], s1, 0, 0, 0);
            }
            __builtin_amdgcn_s_setprio(0);
            float px[32];   // idx = kh*16 + r; k_local = (r&3)+8*(r>>2)+4*hi+32*kh
#pragma unroll
            for (int r = 0; r < 16; r++) { px[r] = s0[r]; px[16 + r] = s1[r]; }
            if (t64 + 63 > qw0) {   // diag tile: causal mask
#pragma unroll
                for (int kh = 0; kh < 2; kh++)
#pragma unroll
                    for (int r = 0; r < 16; r++) {
                        int kg = t64 + kh * 32 + ((r & 3) + 8 * (r >> 2)) + hi4;
                        if (kg > qg) px[kh * 16 + r] = -1e30f;
                    }
            }
            // ---- row max: in-lane tree + one permlane pair-exchange ----
            float tm[16];
#pragma unroll
            for (int i = 0; i < 16; i++) tm[i] = fmaxf(px[i], px[i + 16]);
#pragma unroll
            for (int i = 0; i < 8; i++) tm[i] = fmaxf(tm[i], tm[i + 8]);
#pragma unroll
            for (int i = 0; i < 4; i++) tm[i] = fmaxf(tm[i], tm[i + 4]);
            float lmax = fmaxf(fmaxf(tm[0], tm[1]), fmaxf(tm[2], tm[3]));
            union { float f; unsigned int u; } mb{lmax};
            auto rr = __builtin_amdgcn_permlane32_swap((int)mb.u, (int)mb.u, false, false);
            union { unsigned int u; float f; } ra, rb;
            ra.u = (unsigned int)rr[0];
            rb.u = (unsigned int)rr[1];
            float mn = fmaxf(m, fmaxf(ra.f, rb.f));
            // ---- T13 defer-max: skip rescale when growth <= THR (wave-uniform) ----
            if (!__all(mn - m <= RESCALE_THR)) {
                float corr = EXP2F(m - mn);
                m = mn;
                l *= corr;
#pragma unroll
                for (int dt = 0; dt < 2; dt++)
#pragma unroll
                    for (int r = 0; r < 16; r++) oacc[dt][r] *= corr;
            }
            // ---- p = exp2(s - m); truncate to bf16 for P/l consistency ----
            float p[32], pm[32];
#pragma unroll
            for (int i = 0; i < 32; i++) {
                p[i] = EXP2F(px[i] - m);
                union { float f; unsigned int u; } pu{p[i]};
                pu.u &= 0xFFFF0000u;
                pm[i] = pu.f;
            }
            // ---- row sum: in-lane tree + permlane pair-exchange ----
            float ts[16];
#pragma unroll
            for (int i = 0; i < 16; i++) ts[i] = pm[i] + pm[i + 16];
#pragma unroll
            for (int i = 0; i < 8; i++) ts[i] = ts[i] + ts[i + 8];
#pragma unroll
            for (int i = 0; i < 4; i++) ts[i] = ts[i] + ts[i + 4];
            float lsum = (ts[0] + ts[1]) + (ts[2] + ts[3]);
            union { float f; unsigned int u; } sb{lsum};
            auto rr2 = __builtin_amdgcn_permlane32_swap((int)sb.u, (int)sb.u, false, false);
            union { unsigned int u; float f; } sa2, sb2;
            sa2.u = (unsigned int)rr2[0];
            sb2.u = (unsigned int)rr2[1];
            l = l + (sa2.f + sb2.f);
            // ---- pack P -> bf16 B-fragments (P^T: col=q, k = hi*8+e+16*sl) ----
            short8 pf[4];
#pragma unroll
            for (int kh = 0; kh < 2; kh++)
#pragma unroll
                for (int s = 0; s < 2; s++) {
                    int base = kh * 16 + 8 * s;
                    unsigned int a01 = permpack(p[base + 1], p[base + 0]);
                    unsigned int a23 = permpack(p[base + 3], p[base + 2]);
                    unsigned int a45 = permpack(p[base + 5], p[base + 4]);
                    unsigned int a67 = permpack(p[base + 7], p[base + 6]);
                    auto r02 = __builtin_amdgcn_permlane32_swap((int)a01, (int)a45, false, false);
                    auto r13 = __builtin_amdgcn_permlane32_swap((int)a23, (int)a67, false, false);
                    union { unsigned int wd[4]; short8 v; } pk;
                    pk.wd[0] = (unsigned int)r02[0];
                    pk.wd[1] = (unsigned int)r13[0];
                    pk.wd[2] = (unsigned int)r02[1];
                    pk.wd[3] = (unsigned int)r13[1];
                    pf[kh * 2 + s] = pk.v;
                }
            // ---- O^T += V^T * P^T ----
            __builtin_amdgcn_s_setprio(1);
#pragma unroll
            for (int dt = 0; dt < 2; dt++)
#pragma unroll
                for (int sl = 0; sl < 4; sl++) {
                    short8 va = *(const short8*)&Vt[(dt * 32 + lq) * AST + sl * 16 + hi8];
                    oacc[dt] = __builtin_amdgcn_mfma_f32_32x32x16_bf16(va, pf[sl], oacc[dt], 0, 0, 0);
                }
            __builtin_amdgcn_s_setprio(0);
        }
        // stage tile t+1 into the other buffer; issue tile t+2 global loads
        if (t + 1 < nt) {
            unsigned short* Kn = SM + (par ^ 1) * (2 * 64 * AST);
            commit_pre(Kn, Kn + 64 * AST, tid, pre);
            if (t + 2 < nt) issue_pre(kb, vb, (t + 2) * 64, tid, pre);
        }
        __syncthreads();   // commit visible for t+1; also guards WAR for t+2
    }
    // ---- epilogue: O^T -> per-wave LDS transpose -> coalesced stores ----
    // (loop-end barrier already separates last compute from these writes)
    float inv = 1.f / l;
    unsigned short* Os = SM + w * 32 * AST;    // per-wave 32x72 region (buf0)
#pragma unroll
    for (int dt = 0; dt < 2; dt++)
#pragma unroll
        for (int j = 0; j < 8; j++) {          // r = 2j, 2j+1 -> d, d+1
            int d = dt * 32 + ((2 * j) & 3) + 8 * (j >> 1) + hi4;
            unsigned int pk = (unsigned int)f2bf(oacc[dt][2 * j] * inv)
                            | ((unsigned int)f2bf(oacc[dt][2 * j + 1] * inv) << 16);
            *(unsigned int*)&Os[lq * AST + d] = pk;
        }
    __syncthreads();
#pragma unroll
    for (int j = 0; j < 4; j++) {
        int row = j * 8 + (lane >> 3);
        short8 v = *(const short8*)&Os[row * AST + (lane & 7) * 8];
        int qrow = b * S_LEN + qw0 + row;
        *(short8*)&obf[(size_t)qrow * D_MODEL + h * D_K + (lane & 7) * 8] = v;
    }
}

extern "C" void kernel_launch(void* const* d_in, const int* in_sizes, int n_in,
                              void* d_out, int out_size, void* d_ws, size_t ws_size,
                              hipStream_t stream) {
    const float* x  = (const float*)d_in[0];
    const float* Wq = (const float*)d_in[1];
    const float* bq = (const float*)d_in[2];
    const float* Wk = (const float*)d_in[3];
    const float* bk = (const float*)d_in[4];
    const float* Wv = (const float*)d_in[5];
    const float* bv = (const float*)d_in[6];
    const float* Wo = (const float*)d_in[7];
    const float* bo = (const float*)d_in[8];
    float* out = (float*)d_out;

    // ws (bf16 elems): xbf/obf 8MB | WtQKV 12MB | WtO 8MB | qkv 12MB | bias 12KB
    //                 | rope table 256KB  = ~40.3MB
    unsigned short* xbf   = (unsigned short*)d_ws;                       // [2048][2048]
    unsigned short* WtQKV = xbf + (size_t)M_ROWS * D_MODEL;              // [3072][2048]
    unsigned short* WtO   = WtQKV + (size_t)QKV_N * D_MODEL;             // [2048][2048]
    unsigned short* qkv   = WtO + (size_t)D_MODEL * D_MODEL;             // [2048][3072]
    float* bias_qkv       = (float*)(qkv + (size_t)M_ROWS * QKV_N);      // [3072]
    float2* rtab          = (float2*)(bias_qkv + QKV_N);                 // [1024][32]
    unsigned short* obf   = xbf;  // xbf consumed by QKV GEMM before attn writes

    dim3 gb(256);

    // fused prep: weights transpose (z=0..3) + x cast (z=4..5) + bias/rope (z=6)
    prep_kernel<<<dim3(32, 32, 7), gb, 0, stream>>>(x, Wq, Wk, Wv, Wo, bq, bk, bv,
                                                    xbf, WtQKV, WtO, bias_qkv, rtab);
    // fused QKV projection + RoPE (bf16 out): 48 x 16 = 768 blocks, 2-phase dbuf
    gemm_bf16_kernel<unsigned short, true><<<dim3(QKV_N / 64, M_ROWS / 128), gb, 0, stream>>>(
        xbf, WtQKV, bias_qkv, rtab, qkv, M_ROWS, QKV_N, D_MODEL);
    // attention: 128-row q-tile per block, dbuf K/V (1 barrier/tile), 512 blocks
    attn_mfma_kernel<<<dim3(8, N_HEAD, B_SZ), gb, 0, stream>>>(qkv, obf);
    // O projection (fp32 out): 32 x 16 = 512 blocks, 2-phase dbuf
    gemm_bf16_kernel<float, false><<<dim3(D_MODEL / 64, M_ROWS / 128), gb, 0, stream>>>(
        obf, WtO, bo, nullptr, out, M_ROWS, D_MODEL, D_MODEL);
}

// Round 10
// 211.948 us; speedup vs baseline: 1.1607x; 1.0114x over previous
//
#include <hip/hip_runtime.h>
#include <hip/hip_bf16.h>

#define D_MODEL 2048
#define N_HEAD 32
#define N_KV_HEAD 8
#define N_REP 4
#define D_K 64
#define S_LEN 1024
#define B_SZ 2
#define M_ROWS (B_SZ * S_LEN)      // 2048
#define KV_DIM (N_KV_HEAD * D_K)   // 512
#define QKV_N 3072                 // 2048 q | 512 k | 512 v
#define KOFF 2048
#define VOFF 2560
#define LOG2E 1.44269504088896f
#define TAB_N (S_LEN * 32)         // rope cos/sin table entries

typedef __attribute__((ext_vector_type(8))) short short8;   // 8 bf16 (4 VGPRs)
typedef __attribute__((ext_vector_type(4))) float f32x4;
typedef __attribute__((ext_vector_type(16))) float f32x16;

#define EXP2F(x) __builtin_amdgcn_exp2f(x)   // v_exp_f32 (2^x native)

__device__ inline unsigned short f2bf(float f) {  // RNE fp32 -> bf16 bits
    union { float f; unsigned int u; } x{f};
    unsigned int r = x.u + 0x7fffu + ((x.u >> 16) & 1u);
    return (unsigned short)(r >> 16);
}
__device__ inline float bf2f(unsigned short b) {
    union { unsigned int u; float f; } x; x.u = ((unsigned int)b) << 16; return x.f;
}
__device__ inline void store_c(float* p, float v) { *p = v; }
__device__ inline void store_c(unsigned short* p, float v) { *p = f2bf(v); }

// async 16B global -> LDS (global_load_lds_dwordx4)
__device__ inline void load_lds16(const unsigned short* g, unsigned short* l) {
    __builtin_amdgcn_global_load_lds(
        (const __attribute__((address_space(1))) unsigned int*)g,
        (__attribute__((address_space(3))) unsigned int*)l, 16, 0, 0);
}

// pack two fp32 -> one u32 of 2 bf16 (truncation) via v_perm_b32
__device__ __forceinline__ unsigned int permpack(float hi_f, float lo_f) {
    union { float f; unsigned int u; } a{hi_f}, b{lo_f};
    return __builtin_amdgcn_perm(a.u, b.u, 0x07060302u);
}

// ------- fused prep: z=0..3 weight transpose+cast, z=4..5 x cast, z=6 small ----
__global__ __launch_bounds__(256) void prep_kernel(
        const float* __restrict__ x,
        const float* __restrict__ Wq_, const float* __restrict__ Wk_,
        const float* __restrict__ Wv_, const float* __restrict__ Wo_,
        const float* __restrict__ bq, const float* __restrict__ bk,
        const float* __restrict__ bv,
        unsigned short* __restrict__ xbf,
        unsigned short* __restrict__ WtQKV, unsigned short* __restrict__ WtO,
        float* __restrict__ bias_qkv, float2* __restrict__ rtab) {
    const int z = blockIdx.z;
    if (z == 6) {
        // bias concat + rope cos/sin table
        int i = (blockIdx.y * 32 + blockIdx.x) * 256 + threadIdx.x;
        if (i < QKV_N) {
            bias_qkv[i] = (i < KOFF) ? bq[i] : (i < VOFF) ? bk[i - KOFF] : bv[i - VOFF];
        }
        int j = i - QKV_N;
        if (j >= 0 && j < TAB_N) {
            int s = j >> 5, p = j & 31;
            float invf = EXP2F((float)p * -0.41524101186f);  // theta^(-2p/64)
            float ang = (float)s * invf;
            rtab[j] = make_float2(__cosf(ang), __sinf(ang));
        }
        return;
    }
    if (z >= 4) {
        // cast x (2048x2048 fp32) -> xbf bf16; 2 float4 per thread
        int idx = ((z - 4) * 1024 + blockIdx.y * 32 + blockIdx.x) * 256 + threadIdx.x;
#pragma unroll
        for (int half = 0; half < 2; half++) {
            int i = idx + half * 524288;
            float4 v = ((const float4*)x)[i];
            unsigned int lo = (unsigned int)f2bf(v.x) | ((unsigned int)f2bf(v.y) << 16);
            unsigned int hi = (unsigned int)f2bf(v.z) | ((unsigned int)f2bf(v.w) << 16);
            ((uint2*)xbf)[i] = make_uint2(lo, hi);
        }
        return;
    }
    const float* src; unsigned short* dst; int N;
    switch (z) {
        case 0: src = Wq_; dst = WtQKV; N = D_MODEL; break;
        case 1: src = Wk_; dst = WtQKV + (size_t)KOFF * D_MODEL; N = KV_DIM; break;
        case 2: src = Wv_; dst = WtQKV + (size_t)VOFF * D_MODEL; N = KV_DIM; break;
        default: src = Wo_; dst = WtO; N = D_MODEL; break;
    }
    int n0 = blockIdx.x * 64;
    if (n0 >= N) return;
    int k0 = blockIdx.y * 64;
    int t = threadIdx.x;
    int n = n0 + (t >> 2);
    int ks = k0 + (t & 3) * 16;
    unsigned int pk[8];
#pragma unroll
    for (int i = 0; i < 8; i++) {
        float a = src[(size_t)(ks + 2 * i) * N + n];
        float b = src[(size_t)(ks + 2 * i + 1) * N + n];
        pk[i] = (unsigned int)f2bf(a) | ((unsigned int)f2bf(b) << 16);
    }
    uint4* d = (uint4*)&dst[(size_t)n * D_MODEL + ks];
    d[0] = make_uint4(pk[0], pk[1], pk[2], pk[3]);
    d[1] = make_uint4(pk[4], pk[5], pk[6], pk[7]);
}

// ---------------- bf16 GEMM: C[M,N] = A[M,K] * Bt[N,K]^T + bias ------
// 2-way split-K: 512 thr = 8 waves; waves 0-3 accumulate K[0:K/2] from
// As[0]/Bs[0], waves 4-7 accumulate K[K/2:K] from As[1]/Bs[1]. Per group:
// BM=128, BN=64, BK=64 (proven 0-conflict layout), 2x2 waves of 64x32 out.
// 48 KB LDS -> 3 blocks/CU -> 24 waves/CU (2x the TLP of the 4-wave version)
// and 2x MFMA work per barrier interval -> hides the vmcnt(0) barrier drain.
// Final reduce: group 1 acc -> LDS (reusing As) -> group 0 adds + epilogue.
// ROPE=true (QKV projection): fused rotary embedding in the epilogue; cos/sin
// from the precomputed [1024][32] table; q cols scaled by 0.125*log2e.
template <typename TC, bool ROPE>
__global__ __launch_bounds__(512) void gemm_bf16_kernel(
        const unsigned short* __restrict__ A,   // [M][K] bf16
        const unsigned short* __restrict__ Bt,  // [N][K] bf16
        const float* __restrict__ bias,
        const float2* __restrict__ rtab,
        TC* __restrict__ C, int M, int N, int K) {
    __shared__ unsigned short As[2][128 * 64];  // 32 KB (also reduce buffer)
    __shared__ unsigned short Bs[2][64 * 64];   // 16 KB
    const int tid = threadIdx.x, lane = tid & 63;
    const int w = tid >> 6;
    const int kg = w >> 2, wl = w & 3;          // K-group, wave-in-group
    const int wm = wl >> 1, wn = wl & 1;
    const int lt = tid & 255;                   // thread id within group
    const int quad = lane >> 4, lr = lane & 15;
    const int bm = blockIdx.y * 128, bn = blockIdx.x * 64;
    const int kbase = kg * (K >> 1);

    f32x4 acc[4][2];
#pragma unroll
    for (int i = 0; i < 4; i++)
#pragma unroll
        for (int j = 0; j < 2; j++) acc[i][j] = (f32x4){0.f, 0.f, 0.f, 0.f};

    for (int k0 = 0; k0 < (K >> 1); k0 += 64) {
        __syncthreads();
#pragma unroll
        for (int it = 0; it < 4; it++) {
            int slot = it * 256 + lt;
            int row = slot >> 3;
            int qc = (slot & 7) ^ (row & 7);
            load_lds16(A + (size_t)(bm + row) * K + kbase + k0 + qc * 8, &As[kg][slot * 8]);
        }
#pragma unroll
        for (int it = 0; it < 2; it++) {
            int slot = it * 256 + lt;
            int row = slot >> 3;
            int qc = (slot & 7) ^ (row & 7);
            load_lds16(Bt + (size_t)(bn + row) * K + kbase + k0 + qc * 8, &Bs[kg][slot * 8]);
        }
        __syncthreads();
#pragma unroll
        for (int ks = 0; ks < 2; ks++) {
            short8 af[4], bf[2];
#pragma unroll
            for (int i = 0; i < 4; i++) {
                int row = wm * 64 + i * 16 + lr;
                af[i] = *(const short8*)&As[kg][(row * 8 + ((ks * 4 + quad) ^ (lr & 7))) * 8];
            }
#pragma unroll
            for (int j = 0; j < 2; j++) {
                int row = wn * 32 + j * 16 + lr;
                bf[j] = *(const short8*)&Bs[kg][(row * 8 + ((ks * 4 + quad) ^ (lr & 7))) * 8];
            }
#pragma unroll
            for (int i = 0; i < 4; i++)
#pragma unroll
                for (int j = 0; j < 2; j++)
                    acc[i][j] = __builtin_amdgcn_mfma_f32_16x16x32_bf16(af[i], bf[j], acc[i][j], 0, 0, 0);
        }
    }
    // ---- split-K reduce through LDS (reuse As: 8x256 f32x4 = 32 KB) ----
    __syncthreads();                            // group 0 done reading As/Bs
    f32x4* rbuf = (f32x4*)As;
    if (kg == 1) {
#pragma unroll
        for (int i = 0; i < 4; i++)
#pragma unroll
            for (int j = 0; j < 2; j++)
                rbuf[(i * 2 + j) * 256 + wl * 64 + lane] = acc[i][j];
    }
    __syncthreads();
    if (kg == 1) return;
#pragma unroll
    for (int i = 0; i < 4; i++)
#pragma unroll
        for (int j = 0; j < 2; j++)
            acc[i][j] += rbuf[(i * 2 + j) * 256 + wl * 64 + lane];

#pragma unroll
    for (int i = 0; i < 4; i++) {
#pragma unroll
        for (int j = 0; j < 2; j++) {
            int col = bn + wn * 32 + j * 16 + lr;
            int row0 = bm + wm * 64 + i * 16 + quad * 4;
            float bj = bias[col];
            if constexpr (ROPE) {
                // col class is uniform across the shfl pair (boundaries % 64 == 0)
                bool isv = col >= VOFF;
                bool isq = col < KOFF;
                int ip = (col & 63) >> 1;
                bool even = !(lr & 1);
#pragma unroll
                for (int r = 0; r < 4; r++) {
                    float v = acc[i][j][r] + bj;
                    float pv = __shfl_xor(v, 1);     // partner col^1 (lane^1)
                    float outv = v;
                    if (!isv) {
                        int s = (row0 + r) & (S_LEN - 1);
                        float2 cs = rtab[s * 32 + ip];
                        outv = v * cs.x + (even ? -pv : pv) * cs.y;
                        if (isq) outv *= 0.125f * LOG2E;
                    }
                    store_c(&C[(size_t)(row0 + r) * N + col], outv);
                }
            } else {
#pragma unroll
                for (int r = 0; r < 4; r++)
                    store_c(&C[(size_t)(row0 + r) * N + col], acc[i][j][r] + bj);
            }
        }
    }
}

// ---------------- MFMA flash attention: swapped-operand 32x32, in-reg softmax --
// Block = 256 thr = 4 waves; each wave owns 32 q-rows (block = 128-row q-tile).
// S^T = K*Q^T via mfma_32x32x16 -> lane holds one q-row's 32 scores per kh-half;
// softmax fully in registers (tree reduce + permlane32_swap, zero LDS ops);
// P packed to bf16 in-reg; O^T = V^T*P^T so the online rescale is lane-local.
// K/V LDS double-buffered: ONE barrier per KV tile (compute buf[t&1] ->
// commit buf[t&1^1] -> barrier); a wave's commit overlaps other waves' compute.
// T5 setprio around MFMA clusters; T13 defer-max (THR=8 log2) skips O-rescale.
#define AST 72
#define RESCALE_THR 8.0f
struct Pre { uint4 k0, k1, v0, v1; };

__device__ __forceinline__ void issue_pre(const unsigned short* kb,
                                          const unsigned short* vb,
                                          int j0, int tid, Pre& p) {
    int f0 = tid, f1 = tid + 256;
    p.k0 = *(const uint4*)(kb + (size_t)(j0 + (f0 >> 3)) * QKV_N + (f0 & 7) * 8);
    p.k1 = *(const uint4*)(kb + (size_t)(j0 + (f1 >> 3)) * QKV_N + (f1 & 7) * 8);
    int kp = tid & 31, dg = tid >> 5;
    p.v0 = *(const uint4*)(vb + (size_t)(j0 + 2 * kp) * QKV_N + dg * 8);
    p.v1 = *(const uint4*)(vb + (size_t)(j0 + 2 * kp + 1) * QKV_N + dg * 8);
}
__device__ __forceinline__ void commit_pre(unsigned short* Ks, unsigned short* Vt,
                                           int tid, const Pre& p) {
    int f0 = tid, f1 = tid + 256;
    *(uint4*)&Ks[(f0 >> 3) * AST + (f0 & 7) * 8] = p.k0;
    *(uint4*)&Ks[(f1 >> 3) * AST + (f1 & 7) * 8] = p.k1;
    int kp = tid & 31, dg = tid >> 5;
    const unsigned short* ta = (const unsigned short*)&p.v0;
    const unsigned short* tb = (const unsigned short*)&p.v1;
#pragma unroll
    for (int i = 0; i < 8; i++) {
        unsigned int pk = (unsigned int)ta[i] | ((unsigned int)tb[i] << 16);
        *(unsigned int*)&Vt[(dg * 8 + i) * AST + 2 * kp] = pk;
    }
}

__global__ __launch_bounds__(256) void attn_mfma_kernel(
        const unsigned short* __restrict__ qkv,   // [M_ROWS][QKV_N] bf16
        unsigned short* __restrict__ obf) {       // [M_ROWS][D_MODEL] bf16
    __shared__ unsigned short SM[4 * 64 * AST];   // {Ks|Vt} x2 (buf0 reused for O)
    const int tid = threadIdx.x;
    const int w = tid >> 6, lane = tid & 63;
    const int lq = lane & 31, hi = lane >> 5;
    const int hi8 = hi * 8, hi4 = hi * 4;
    const int h = blockIdx.y, b = blockIdx.z;
    const int kvh = h >> 2;
    const unsigned short* kb = qkv + (size_t)(b * S_LEN) * QKV_N + KOFF + kvh * D_K;
    const unsigned short* vb = qkv + (size_t)(b * S_LEN) * QKV_N + VOFF + kvh * D_K;

    // causal balance: co-resident blocks (ids 256 apart) differ in b -> flip qt
    const int qt = b ? 7 - (int)blockIdx.x : (int)blockIdx.x;   // 0..7
    const int nt = 2 * qt + 2;
    const int qw0 = qt * 128 + w * 32;   // this wave's first q-row
    const int qg = qw0 + lq;             // this lane's q-row

    short8 aq[4];   // Q[qg][d]: d = hi*8 + {0..7} + 16*step
    {
        const unsigned short* qp = qkv + (size_t)(b * S_LEN + qg) * QKV_N + h * D_K + hi8;
#pragma unroll
        for (int st = 0; st < 4; st++) aq[st] = *(const short8*)(qp + st * 16);
    }
    f32x16 oacc[2];   // O^T: col=q(lane), row=d=crow(r,hi)+32*dt
#pragma unroll
    for (int dt = 0; dt < 2; dt++)
#pragma unroll
        for (int r = 0; r < 16; r++) oacc[dt][r] = 0.f;
    float m = -1e30f, l = 0.f;

    Pre pre;
    issue_pre(kb, vb, 0, tid, pre);
    commit_pre(SM, SM + 64 * AST, tid, pre);           // tile 0 -> buf0
    if (nt > 1) issue_pre(kb, vb, 64, tid, pre);       // tile 1 -> regs
    __syncthreads();                                   // buf0 visible

    for (int t = 0; t < nt; t++) {
        const int par = t & 1;
        unsigned short* Ks = SM + par * (2 * 64 * AST);
        unsigned short* Vt = Ks + 64 * AST;
        const int t64 = t * 64;
        if (t64 <= qw0 + 31) {
            // ---- S^T = K * Q^T  (rows k, cols q=lane) ----
            f32x16 s0, s1;
#pragma unroll
            for (int r = 0; r < 16; r++) { s0[r] = 0.f; s1[r] = 0.f; }
            __builtin_amdgcn_s_setprio(1);
#pragma unroll
            for (int st = 0; st < 4; st++) {
                short8 k0 = *(const short8*)&Ks[lq * AST + st * 16 + hi8];
                short8 k1 = *(const short8*)&Ks[(32 + lq) * AST + st * 16 + hi8];
                s0 = __builtin_amdgcn_mfma_f32_32x32x16_bf16(k0, aq[st], s0, 0, 0, 0);
                s1 = __builtin_amdgcn_mfma_f32_32x32x16_bf16(k1, aq[st], s1, 0, 0, 0);
            }
            __builtin_amdgcn_s_setprio(0);
            float px[32];   // idx = kh*16 + r; k_local = (r&3)+8*(r>>2)+4*hi+32*kh
#pragma unroll
            for (int r = 0; r < 16; r++) { px[r] = s0[r]; px[16 + r] = s1[r]; }
            if (t64 + 63 > qw0) {   // diag tile: causal mask
#pragma unroll
                for (int kh = 0; kh < 2; kh++)
#pragma unroll
                    for (int r = 0; r < 16; r++) {
                        int kg = t64 + kh * 32 + ((r & 3) + 8 * (r >> 2)) + hi4;
                        if (kg > qg) px[kh * 16 + r] = -1e30f;
                    }
            }
            // ---- row max: in-lane tree + one permlane pair-exchange ----
            float tm[16];
#pragma unroll
            for (int i = 0; i < 16; i++) tm[i] = fmaxf(px[i], px[i + 16]);
#pragma unroll
            for (int i = 0; i < 8; i++) tm[i] = fmaxf(tm[i], tm[i + 8]);
#pragma unroll
            for (int i = 0; i < 4; i++) tm[i] = fmaxf(tm[i], tm[i + 4]);
            float lmax = fmaxf(fmaxf(tm[0], tm[1]), fmaxf(tm[2], tm[3]));
            union { float f; unsigned int u; } mb{lmax};
            auto rr = __builtin_amdgcn_permlane32_swap((int)mb.u, (int)mb.u, false, false);
            union { unsigned int u; float f; } ra, rb;
            ra.u = (unsigned int)rr[0];
            rb.u = (unsigned int)rr[1];
            float mn = fmaxf(m, fmaxf(ra.f, rb.f));
            // ---- T13 defer-max: skip rescale when growth <= THR (wave-uniform) ----
            if (!__all(mn - m <= RESCALE_THR)) {
                float corr = EXP2F(m - mn);
                m = mn;
                l *= corr;
#pragma unroll
                for (int dt = 0; dt < 2; dt++)
#pragma unroll
                    for (int r = 0; r < 16; r++) oacc[dt][r] *= corr;
            }
            // ---- p = exp2(s - m); truncate to bf16 for P/l consistency ----
            float p[32], pm[32];
#pragma unroll
            for (int i = 0; i < 32; i++) {
                p[i] = EXP2F(px[i] - m);
                union { float f; unsigned int u; } pu{p[i]};
                pu.u &= 0xFFFF0000u;
                pm[i] = pu.f;
            }
            // ---- row sum: in-lane tree + permlane pair-exchange ----
            float ts[16];
#pragma unroll
            for (int i = 0; i < 16; i++) ts[i] = pm[i] + pm[i + 16];
#pragma unroll
            for (int i = 0; i < 8; i++) ts[i] = ts[i] + ts[i + 8];
#pragma unroll
            for (int i = 0; i < 4; i++) ts[i] = ts[i] + ts[i + 4];
            float lsum = (ts[0] + ts[1]) + (ts[2] + ts[3]);
            union { float f; unsigned int u; } sb{lsum};
            auto rr2 = __builtin_amdgcn_permlane32_swap((int)sb.u, (int)sb.u, false, false);
            union { unsigned int u; float f; } sa2, sb2;
            sa2.u = (unsigned int)rr2[0];
            sb2.u = (unsigned int)rr2[1];
            l = l + (sa2.f + sb2.f);
            // ---- pack P -> bf16 B-fragments (P^T: col=q, k = hi*8+e+16*sl) ----
            short8 pf[4];
#pragma unroll
            for (int kh = 0; kh < 2; kh++)
#pragma unroll
                for (int s = 0; s < 2; s++) {
                    int base = kh * 16 + 8 * s;
                    unsigned int a01 = permpack(p[base + 1], p[base + 0]);
                    unsigned int a23 = permpack(p[base + 3], p[base + 2]);
                    unsigned int a45 = permpack(p[base + 5], p[base + 4]);
                    unsigned int a67 = permpack(p[base + 7], p[base + 6]);
                    auto r02 = __builtin_amdgcn_permlane32_swap((int)a01, (int)a45, false, false);
                    auto r13 = __builtin_amdgcn_permlane32_swap((int)a23, (int)a67, false, false);
                    union { unsigned int wd[4]; short8 v; } pk;
                    pk.wd[0] = (unsigned int)r02[0];
                    pk.wd[1] = (unsigned int)r13[0];
                    pk.wd[2] = (unsigned int)r02[1];
                    pk.wd[3] = (unsigned int)r13[1];
                    pf[kh * 2 + s] = pk.v;
                }
            // ---- O^T += V^T * P^T ----
            __builtin_amdgcn_s_setprio(1);
#pragma unroll
            for (int dt = 0; dt < 2; dt++)
#pragma unroll
                for (int sl = 0; sl < 4; sl++) {
                    short8 va = *(const short8*)&Vt[(dt * 32 + lq) * AST + sl * 16 + hi8];
                    oacc[dt] = __builtin_amdgcn_mfma_f32_32x32x16_bf16(va, pf[sl], oacc[dt], 0, 0, 0);
                }
            __builtin_amdgcn_s_setprio(0);
        }
        // stage tile t+1 into the other buffer; issue tile t+2 global loads
        if (t + 1 < nt) {
            unsigned short* Kn = SM + (par ^ 1) * (2 * 64 * AST);
            commit_pre(Kn, Kn + 64 * AST, tid, pre);
            if (t + 2 < nt) issue_pre(kb, vb, (t + 2) * 64, tid, pre);
        }
        __syncthreads();   // commit visible for t+1; also guards WAR for t+2
    }
    // ---- epilogue: O^T -> per-wave LDS transpose -> coalesced stores ----
    // (loop-end barrier already separates last compute from these writes)
    float inv = 1.f / l;
    unsigned short* Os = SM + w * 32 * AST;    // per-wave 32x72 region (buf0)
#pragma unroll
    for (int dt = 0; dt < 2; dt++)
#pragma unroll
        for (int j = 0; j < 8; j++) {          // r = 2j, 2j+1 -> d, d+1
            int d = dt * 32 + ((2 * j) & 3) + 8 * (j >> 1) + hi4;
            unsigned int pk = (unsigned int)f2bf(oacc[dt][2 * j] * inv)
                            | ((unsigned int)f2bf(oacc[dt][2 * j + 1] * inv) << 16);
            *(unsigned int*)&Os[lq * AST + d] = pk;
        }
    __syncthreads();
#pragma unroll
    for (int j = 0; j < 4; j++) {
        int row = j * 8 + (lane >> 3);
        short8 v = *(const short8*)&Os[row * AST + (lane & 7) * 8];
        int qrow = b * S_LEN + qw0 + row;
        *(short8*)&obf[(size_t)qrow * D_MODEL + h * D_K + (lane & 7) * 8] = v;
    }
}

extern "C" void kernel_launch(void* const* d_in, const int* in_sizes, int n_in,
                              void* d_out, int out_size, void* d_ws, size_t ws_size,
                              hipStream_t stream) {
    const float* x  = (const float*)d_in[0];
    const float* Wq = (const float*)d_in[1];
    const float* bq = (const float*)d_in[2];
    const float* Wk = (const float*)d_in[3];
    const float* bk = (const float*)d_in[4];
    const float* Wv = (const float*)d_in[5];
    const float* bv = (const float*)d_in[6];
    const float* Wo = (const float*)d_in[7];
    const float* bo = (const float*)d_in[8];
    float* out = (float*)d_out;

    // ws (bf16 elems): xbf/obf 8MB | WtQKV 12MB | WtO 8MB | qkv 12MB | bias 12KB
    //                 | rope table 256KB  = ~40.3MB
    unsigned short* xbf   = (unsigned short*)d_ws;                       // [2048][2048]
    unsigned short* WtQKV = xbf + (size_t)M_ROWS * D_MODEL;              // [3072][2048]
    unsigned short* WtO   = WtQKV + (size_t)QKV_N * D_MODEL;             // [2048][2048]
    unsigned short* qkv   = WtO + (size_t)D_MODEL * D_MODEL;             // [2048][3072]
    float* bias_qkv       = (float*)(qkv + (size_t)M_ROWS * QKV_N);      // [3072]
    float2* rtab          = (float2*)(bias_qkv + QKV_N);                 // [1024][32]
    unsigned short* obf   = xbf;  // xbf consumed by QKV GEMM before attn writes

    dim3 gb(256);
    dim3 gg(512);

    // fused prep: weights transpose (z=0..3) + x cast (z=4..5) + bias/rope (z=6)
    prep_kernel<<<dim3(32, 32, 7), gb, 0, stream>>>(x, Wq, Wk, Wv, Wo, bq, bk, bv,
                                                    xbf, WtQKV, WtO, bias_qkv, rtab);
    // fused QKV projection + RoPE (bf16 out): 48 x 16 = 768 blocks, split-K x2
    gemm_bf16_kernel<unsigned short, true><<<dim3(QKV_N / 64, M_ROWS / 128), gg, 0, stream>>>(
        xbf, WtQKV, bias_qkv, rtab, qkv, M_ROWS, QKV_N, D_MODEL);
    // attention: 128-row q-tile per block, dbuf K/V (1 barrier/tile), 512 blocks
    attn_mfma_kernel<<<dim3(8, N_HEAD, B_SZ), gb, 0, stream>>>(qkv, obf);
    // O projection (fp32 out): 32 x 16 = 512 blocks, split-K x2
    gemm_bf16_kernel<float, false><<<dim3(D_MODEL / 64, M_ROWS / 128), gg, 0, stream>>>(
        obf, WtO, bo, nullptr, out, M_ROWS, D_MODEL, D_MODEL);
}